// Round 5
// baseline (2571.254 us; speedup 1.0000x reference)
//
#include <hip/hip_runtime.h>

#define EPS 1e-7f

constexpr int B = 8, C = 64, H = 256, W = 448;
constexpr int N = H * W;          // 114688
constexpr int P = B * N;          // 917504

constexpr int TH = 32, TW = 32;   // exclusive output tile
constexpr int R  = 6;             // halo radius (covers |flow| <= 5)
constexpr int WH = TH + 2 * R;    // 44
constexpr int WW = TW + 2 * R;    // 44 (compile-time divisor)
constexpr int NSRC = WH * WW;     // 1936
constexpr int NT = 512;
constexpr int PS = TW + 4;        // 36: float4-aligned pad, rotates banks per row
constexpr int PLANE = TH * PS;    // 1152 words
constexpr int NCH = 8;            // channels per chunk block; LDS = 36,864 B -> 4 blocks/CU
constexpr int TILES_X = W / TW, TILES_Y = H / TH;   // 14, 8
constexpr int TILES = B * TILES_X * TILES_Y;        // 896
constexpr float FMAX = (float)(R - 1);              // 5.0

__global__ __launch_bounds__(NT, 4) void softsplat_gather(
    const float* __restrict__ x,
    const float* __restrict__ flow,
    const float* __restrict__ metric,
    float* __restrict__ out,      // [B, C, N] numerator
    float* __restrict__ den)      // [B, N]    denominator
{
    __shared__ float acc[NCH * PLANE];   // 36,864 B

    const int tile  = blockIdx.x;
    const int chunk = blockIdx.y;        // 0..7 = channel chunks, 8 = denominator
    const int b  = tile / (TILES_X * TILES_Y);
    const int tp = tile % (TILES_X * TILES_Y);
    const int r0 = (tp / TILES_X) * TH;
    const int c0 = (tp % TILES_X) * TW;
    const int tid = threadIdx.x;
    const bool isden = (chunk == NCH);

    const int nwords = isden ? PLANE : NCH * PLANE;
    for (int i = tid; i < nwords; i += NT) acc[i] = 0.f;
    __syncthreads();

    const float* fx_p = flow + (size_t)(b * 2 + 0) * N;
    const float* fy_p = flow + (size_t)(b * 2 + 1) * N;
    const float* m_p  = metric + (size_t)b * N;
    const float* xb   = x + ((size_t)b * C + (isden ? 0 : chunk * NCH)) * N;

    // branch-free main loop: weights zeroed for any invalid condition,
    // indices clamped into the LDS plane, atomics unconditional.
    for (int s = tid; s < NSRC; s += NT) {
        const int wy = s / WW;            // compile-time divisor -> magic mul
        const int wx = s - wy * WW;
        const int sh = r0 - R + wy;
        const int sw = c0 - R + wx;
        const bool vsrc = (sh >= 0) & (sh < H) & (sw >= 0) & (sw < W);
        const int sp = vsrc ? sh * W + sw : 0;

        const float fdx = fx_p[sp], fdy = fy_p[sp];
        // |flow|>FMAX handled exactly by the outlier fixup pass
        const bool ok = vsrc & (fabsf(fdx) <= FMAX) & (fabsf(fdy) <= FMAX);

        const float tx = (float)sw + fdx, ty = (float)sh + fdy;
        const float x0f = floorf(tx), y0f = floorf(ty);
        const int lx0 = (int)x0f - c0, ly0 = (int)y0f - r0;
        const int lx1 = lx0 + 1,       ly1 = ly0 + 1;
        const bool vx0 = (unsigned)lx0 < (unsigned)TW;
        const bool vx1 = (unsigned)lx1 < (unsigned)TW;
        const bool vy0 = (unsigned)ly0 < (unsigned)TH;
        const bool vy1 = (unsigned)ly1 < (unsigned)TH;

        const float m  = ok ? __expf(m_p[sp]) : 0.f;
        const float fxf = tx - x0f, fyf = ty - y0f;
        const float w0 = (vx0 && vy0) ? (1.f - fxf) * (1.f - fyf) * m : 0.f;
        const float w1 = (vx1 && vy0) ? fxf * (1.f - fyf) * m : 0.f;
        const float w2 = (vx0 && vy1) ? (1.f - fxf) * fyf * m : 0.f;
        const float w3 = (vx1 && vy1) ? fxf * fyf * m : 0.f;

        const int cx0 = min(max(lx0, 0), TW - 1), cx1 = min(max(lx1, 0), TW - 1);
        const int cy0 = min(max(ly0, 0), TH - 1), cy1 = min(max(ly1, 0), TH - 1);
        const int i00 = cy0 * PS + cx0, i10 = cy0 * PS + cx1;
        const int i01 = cy1 * PS + cx0, i11 = cy1 * PS + cx1;

        if (isden) {   // block-uniform branch
            atomicAdd(acc + i00, w0);
            atomicAdd(acc + i10, w1);
            atomicAdd(acc + i01, w2);
            atomicAdd(acc + i11, w3);
        } else {
            #pragma unroll
            for (int c = 0; c < NCH; ++c) {
                const float v = xb[(size_t)c * N + sp];
                float* pl = acc + c * PLANE;   // c*PLANE*4 < 64KB: folds into ds offset
                atomicAdd(pl + i00, v * w0);
                atomicAdd(pl + i10, v * w1);
                atomicAdd(pl + i01, v * w2);
                atomicAdd(pl + i11, v * w3);
            }
        }
    }
    __syncthreads();

    // non-atomic coalesced float4 writeback of the exclusive tile
    if (isden) {
        float* db = den + (size_t)b * N;
        for (int k = tid; k < TH * (TW / 4); k += NT) {
            const int yy = k / (TW / 4), xg = k % (TW / 4);
            const float* src = acc + yy * PS + xg * 4;
            *reinterpret_cast<float4*>(db + (size_t)(r0 + yy) * W + c0 + xg * 4) =
                make_float4(src[0], src[1], src[2], src[3]);
        }
    } else {
        for (int k = tid; k < NCH * TH * (TW / 4); k += NT) {
            const int c   = k / (TH * (TW / 4));
            const int rem = k % (TH * (TW / 4));
            const int yy  = rem / (TW / 4), xg = rem % (TW / 4);
            const float* src = acc + c * PLANE + yy * PS + xg * 4;
            *reinterpret_cast<float4*>(
                out + ((size_t)(b * C + chunk * NCH + c) * H + r0 + yy) * W + c0 + xg * 4) =
                make_float4(src[0], src[1], src[2], src[3]);
        }
    }
}

// Exact complement of the gather's skip predicate; global atomics on top.
__global__ __launch_bounds__(256) void softsplat_outlier(
    const float* __restrict__ x,
    const float* __restrict__ flow,
    const float* __restrict__ metric,
    float* __restrict__ out,
    float* __restrict__ den)
{
    int t = blockIdx.x * blockDim.x + threadIdx.x;
    if (t >= P) return;
    int b = t / N;
    int p = t - b * N;
    float fdx = flow[(size_t)(b * 2 + 0) * N + p];
    float fdy = flow[(size_t)(b * 2 + 1) * N + p];
    if (fabsf(fdx) <= FMAX && fabsf(fdy) <= FMAX) return;

    int h = p / W, w = p - h * W;
    float m = __expf(metric[(size_t)b * N + p]);
    float tx = (float)w + fdx, ty = (float)h + fdy;
    float x0f = floorf(tx), y0f = floorf(ty);
    int x0 = (int)x0f, y0 = (int)y0f, x1 = x0 + 1, y1 = y0 + 1;
    float fx = tx - x0f, fy = ty - y0f;
    float w00 = (1.f - fx) * (1.f - fy), w10 = fx * (1.f - fy);
    float w01 = (1.f - fx) * fy,         w11 = fx * fy;
    bool vx0 = (x0 >= 0) && (x0 < W), vx1 = (x1 >= 0) && (x1 < W);
    bool vy0 = (y0 >= 0) && (y0 < H), vy1 = (y1 >= 0) && (y1 < H);
    int cx0 = min(max(x0, 0), W - 1), cx1 = min(max(x1, 0), W - 1);
    int cy0 = min(max(y0, 0), H - 1), cy1 = min(max(y1, 0), H - 1);
    int i00 = cy0 * W + cx0, i10 = cy0 * W + cx1;
    int i01 = cy1 * W + cx0, i11 = cy1 * W + cx1;
    w00 = (vx0 && vy0) ? w00 * m : 0.f;
    w10 = (vx1 && vy0) ? w10 * m : 0.f;
    w01 = (vx0 && vy1) ? w01 * m : 0.f;
    w11 = (vx1 && vy1) ? w11 * m : 0.f;

    float* denb = den + (size_t)b * N;
    if (w00 != 0.f) atomicAdd(denb + i00, w00);
    if (w10 != 0.f) atomicAdd(denb + i10, w10);
    if (w01 != 0.f) atomicAdd(denb + i01, w01);
    if (w11 != 0.f) atomicAdd(denb + i11, w11);

    const float* xb = x + (size_t)b * C * N + p;
    float* ob = out + (size_t)b * C * N;
    for (int c = 0; c < C; ++c) {
        float v = xb[(size_t)c * N];
        float* o = ob + (size_t)c * N;
        if (w00 != 0.f) atomicAdd(o + i00, v * w00);
        if (w10 != 0.f) atomicAdd(o + i10, v * w10);
        if (w01 != 0.f) atomicAdd(o + i01, v * w01);
        if (w11 != 0.f) atomicAdd(o + i11, v * w11);
    }
}

__global__ __launch_bounds__(256) void softsplat_norm(
    float* __restrict__ out, const float* __restrict__ den)
{
    size_t t = (size_t)blockIdx.x * blockDim.x + threadIdx.x;  // one float4
    size_t e = t * 4;
    if (e >= (size_t)B * C * N) return;
    size_t b = e / ((size_t)C * N);
    size_t p = (e - b * (size_t)C * N) % N;   // N % 4 == 0

    float4 o = *reinterpret_cast<float4*>(out + e);
    const float4 d = *reinterpret_cast<const float4*>(den + b * N + p);
    o.x = o.x / (d.x + EPS);
    o.y = o.y / (d.y + EPS);
    o.z = o.z / (d.z + EPS);
    o.w = o.w / (d.w + EPS);
    *reinterpret_cast<float4*>(out + e) = o;
}

extern "C" void kernel_launch(void* const* d_in, const int* in_sizes, int n_in,
                              void* d_out, int out_size, void* d_ws, size_t ws_size,
                              hipStream_t stream) {
    const float* x      = (const float*)d_in[0];
    const float* flow   = (const float*)d_in[1];
    const float* metric = (const float*)d_in[2];
    float* out = (float*)d_out;
    float* den = (float*)d_ws;

    dim3 grid(TILES, NCH + 1);   // 896 tiles x (8 channel chunks + 1 den)
    softsplat_gather<<<grid, NT, 0, stream>>>(x, flow, metric, out, den);

    softsplat_outlier<<<(P + 255) / 256, 256, 0, stream>>>(x, flow, metric, out, den);

    size_t nvec4 = (size_t)B * C * N / 4;
    softsplat_norm<<<(int)((nvec4 + 255) / 256), 256, 0, stream>>>(out, den);
}

// Round 6
// 2225.963 us; speedup vs baseline: 1.1551x; 1.1551x over previous
//
#include <hip/hip_runtime.h>

#define EPS 1e-7f

constexpr int B = 8, C = 64, H = 256, W = 448;
constexpr int N = H * W;          // 114688
constexpr int P = B * N;          // 917504

constexpr int TH = 32, TW = 64;   // exclusive output tile
constexpr int R  = 6;             // halo radius (covers |flow| <= 5)
constexpr int WH = TH + 2 * R;    // 44
constexpr int WW = TW + 2 * R;    // 76 (compile-time divisor -> magic mul)
constexpr int NSRC = WH * WW;     // 3344
constexpr int NT = 1024;          // 16 waves/block x 2 blocks/CU -> 32 waves/CU
constexpr int PS = TW + 4;        // 68: float4-aligned pad
constexpr int PLANE = TH * PS;    // 2176 words
constexpr int NCH = 8;            // channels per chunk block; LDS = 69,632 B
constexpr int TILES_X = W / TW, TILES_Y = H / TH;   // 7, 8
constexpr int TILES = B * TILES_X * TILES_Y;        // 448
constexpr float FMAX = (float)(R - 1);              // 5.0

// NOTE: single-arg launch_bounds only. Two-arg variants (1024,8) and (512,4)
// both made the allocator emit a 12-VGPR / all-scratch kernel (rounds 4,5).
__global__ __launch_bounds__(NT) void softsplat_gather(
    const float* __restrict__ x,
    const float* __restrict__ flow,
    const float* __restrict__ metric,
    float* __restrict__ out,      // [B, C, N] numerator
    float* __restrict__ den)      // [B, N]    denominator
{
    __shared__ float acc[NCH * PLANE];   // 69,632 B -> 2 blocks/CU

    const int tile  = blockIdx.x;
    const int chunk = blockIdx.y;        // 0..7 = channel chunks, 8 = denominator
    const int b  = tile / (TILES_X * TILES_Y);
    const int tp = tile % (TILES_X * TILES_Y);
    const int r0 = (tp / TILES_X) * TH;
    const int c0 = (tp % TILES_X) * TW;
    const int tid = threadIdx.x;
    const bool isden = (chunk == NCH);

    const int nwords = isden ? PLANE : NCH * PLANE;
    for (int i = tid; i < nwords; i += NT) acc[i] = 0.f;
    __syncthreads();

    const float* fx_p = flow + (size_t)(b * 2 + 0) * N;
    const float* fy_p = flow + (size_t)(b * 2 + 1) * N;
    const float* m_p  = metric + (size_t)b * N;
    const float* xb   = x + ((size_t)b * C + (isden ? 0 : chunk * NCH)) * N;

    // branch-free main loop: weights zeroed for any invalid condition,
    // indices clamped into the LDS plane, atomics unconditional -> the
    // compiler can software-pipeline the independent loads.
    for (int s = tid; s < NSRC; s += NT) {
        const int wy = s / WW;            // compile-time divisor
        const int wx = s - wy * WW;
        const int sh = r0 - R + wy;
        const int sw = c0 - R + wx;
        const bool vsrc = (sh >= 0) & (sh < H) & (sw >= 0) & (sw < W);
        const int sp = vsrc ? sh * W + sw : 0;

        const float fdx = fx_p[sp], fdy = fy_p[sp];
        // |flow|>FMAX handled exactly by the outlier fixup pass
        const bool ok = vsrc & (fabsf(fdx) <= FMAX) & (fabsf(fdy) <= FMAX);

        const float tx = (float)sw + fdx, ty = (float)sh + fdy;
        const float x0f = floorf(tx), y0f = floorf(ty);
        const int lx0 = (int)x0f - c0, ly0 = (int)y0f - r0;
        const int lx1 = lx0 + 1,       ly1 = ly0 + 1;
        const bool vx0 = (unsigned)lx0 < (unsigned)TW;
        const bool vx1 = (unsigned)lx1 < (unsigned)TW;
        const bool vy0 = (unsigned)ly0 < (unsigned)TH;
        const bool vy1 = (unsigned)ly1 < (unsigned)TH;

        const float m  = ok ? __expf(m_p[sp]) : 0.f;
        const float fxf = tx - x0f, fyf = ty - y0f;
        const float w0 = (vx0 && vy0) ? (1.f - fxf) * (1.f - fyf) * m : 0.f;
        const float w1 = (vx1 && vy0) ? fxf * (1.f - fyf) * m : 0.f;
        const float w2 = (vx0 && vy1) ? (1.f - fxf) * fyf * m : 0.f;
        const float w3 = (vx1 && vy1) ? fxf * fyf * m : 0.f;

        const int cx0 = min(max(lx0, 0), TW - 1), cx1 = min(max(lx1, 0), TW - 1);
        const int cy0 = min(max(ly0, 0), TH - 1), cy1 = min(max(ly1, 0), TH - 1);
        const int i00 = cy0 * PS + cx0, i10 = cy0 * PS + cx1;
        const int i01 = cy1 * PS + cx0, i11 = cy1 * PS + cx1;

        if (isden) {   // block-uniform branch
            atomicAdd(acc + i00, w0);
            atomicAdd(acc + i10, w1);
            atomicAdd(acc + i01, w2);
            atomicAdd(acc + i11, w3);
        } else {
            #pragma unroll
            for (int c = 0; c < NCH; ++c) {
                const float v = xb[(size_t)c * N + sp];
                float* pl = acc + c * PLANE;   // c*PLANE*4 folds into ds offset imm
                atomicAdd(pl + i00, v * w0);
                atomicAdd(pl + i10, v * w1);
                atomicAdd(pl + i01, v * w2);
                atomicAdd(pl + i11, v * w3);
            }
        }
    }
    __syncthreads();

    // non-atomic coalesced float4 writeback of the exclusive tile
    if (isden) {
        float* db = den + (size_t)b * N;
        for (int k = tid; k < TH * (TW / 4); k += NT) {
            const int yy = k / (TW / 4), xg = k % (TW / 4);
            const float* src = acc + yy * PS + xg * 4;
            *reinterpret_cast<float4*>(db + (size_t)(r0 + yy) * W + c0 + xg * 4) =
                make_float4(src[0], src[1], src[2], src[3]);
        }
    } else {
        for (int k = tid; k < NCH * TH * (TW / 4); k += NT) {
            const int c   = k / (TH * (TW / 4));
            const int rem = k % (TH * (TW / 4));
            const int yy  = rem / (TW / 4), xg = rem % (TW / 4);
            const float* src = acc + c * PLANE + yy * PS + xg * 4;
            *reinterpret_cast<float4*>(
                out + ((size_t)(b * C + chunk * NCH + c) * H + r0 + yy) * W + c0 + xg * 4) =
                make_float4(src[0], src[1], src[2], src[3]);
        }
    }
}

// Exact complement of the gather's skip predicate; global atomics on top.
__global__ __launch_bounds__(256) void softsplat_outlier(
    const float* __restrict__ x,
    const float* __restrict__ flow,
    const float* __restrict__ metric,
    float* __restrict__ out,
    float* __restrict__ den)
{
    int t = blockIdx.x * blockDim.x + threadIdx.x;
    if (t >= P) return;
    int b = t / N;
    int p = t - b * N;
    float fdx = flow[(size_t)(b * 2 + 0) * N + p];
    float fdy = flow[(size_t)(b * 2 + 1) * N + p];
    if (fabsf(fdx) <= FMAX && fabsf(fdy) <= FMAX) return;

    int h = p / W, w = p - h * W;
    float m = __expf(metric[(size_t)b * N + p]);
    float tx = (float)w + fdx, ty = (float)h + fdy;
    float x0f = floorf(tx), y0f = floorf(ty);
    int x0 = (int)x0f, y0 = (int)y0f, x1 = x0 + 1, y1 = y0 + 1;
    float fx = tx - x0f, fy = ty - y0f;
    float w00 = (1.f - fx) * (1.f - fy), w10 = fx * (1.f - fy);
    float w01 = (1.f - fx) * fy,         w11 = fx * fy;
    bool vx0 = (x0 >= 0) && (x0 < W), vx1 = (x1 >= 0) && (x1 < W);
    bool vy0 = (y0 >= 0) && (y0 < H), vy1 = (y1 >= 0) && (y1 < H);
    int cx0 = min(max(x0, 0), W - 1), cx1 = min(max(x1, 0), W - 1);
    int cy0 = min(max(y0, 0), H - 1), cy1 = min(max(y1, 0), H - 1);
    int i00 = cy0 * W + cx0, i10 = cy0 * W + cx1;
    int i01 = cy1 * W + cx0, i11 = cy1 * W + cx1;
    w00 = (vx0 && vy0) ? w00 * m : 0.f;
    w10 = (vx1 && vy0) ? w10 * m : 0.f;
    w01 = (vx0 && vy1) ? w01 * m : 0.f;
    w11 = (vx1 && vy1) ? w11 * m : 0.f;

    float* denb = den + (size_t)b * N;
    if (w00 != 0.f) atomicAdd(denb + i00, w00);
    if (w10 != 0.f) atomicAdd(denb + i10, w10);
    if (w01 != 0.f) atomicAdd(denb + i01, w01);
    if (w11 != 0.f) atomicAdd(denb + i11, w11);

    const float* xb = x + (size_t)b * C * N + p;
    float* ob = out + (size_t)b * C * N;
    for (int c = 0; c < C; ++c) {
        float v = xb[(size_t)c * N];
        float* o = ob + (size_t)c * N;
        if (w00 != 0.f) atomicAdd(o + i00, v * w00);
        if (w10 != 0.f) atomicAdd(o + i10, v * w10);
        if (w01 != 0.f) atomicAdd(o + i01, v * w01);
        if (w11 != 0.f) atomicAdd(o + i11, v * w11);
    }
}

__global__ __launch_bounds__(256) void softsplat_norm(
    float* __restrict__ out, const float* __restrict__ den)
{
    size_t t = (size_t)blockIdx.x * blockDim.x + threadIdx.x;  // one float4
    size_t e = t * 4;
    if (e >= (size_t)B * C * N) return;
    size_t b = e / ((size_t)C * N);
    size_t p = (e - b * (size_t)C * N) % N;   // N % 4 == 0

    float4 o = *reinterpret_cast<float4*>(out + e);
    const float4 d = *reinterpret_cast<const float4*>(den + b * N + p);
    o.x = o.x / (d.x + EPS);
    o.y = o.y / (d.y + EPS);
    o.z = o.z / (d.z + EPS);
    o.w = o.w / (d.w + EPS);
    *reinterpret_cast<float4*>(out + e) = o;
}

extern "C" void kernel_launch(void* const* d_in, const int* in_sizes, int n_in,
                              void* d_out, int out_size, void* d_ws, size_t ws_size,
                              hipStream_t stream) {
    const float* x      = (const float*)d_in[0];
    const float* flow   = (const float*)d_in[1];
    const float* metric = (const float*)d_in[2];
    float* out = (float*)d_out;
    float* den = (float*)d_ws;

    dim3 grid(TILES, NCH + 1);   // 448 tiles x (8 channel chunks + 1 den)
    softsplat_gather<<<grid, NT, 0, stream>>>(x, flow, metric, out, den);

    softsplat_outlier<<<(P + 255) / 256, 256, 0, stream>>>(x, flow, metric, out, den);

    size_t nvec4 = (size_t)B * C * N / 4;
    softsplat_norm<<<(int)((nvec4 + 255) / 256), 256, 0, stream>>>(out, den);
}

// Round 7
// 1303.294 us; speedup vs baseline: 1.9729x; 1.7080x over previous
//
#include <hip/hip_runtime.h>

#define EPS 1e-7f

constexpr int B = 8, C = 64, H = 256, W = 448;
constexpr int N = H * W;          // 114688
constexpr int P = B * N;          // 917504

constexpr int TH = 32, TW = 64;   // exclusive output tile
constexpr int R  = 8;             // halo radius (covers |flow| <= 7)
constexpr int PS = TW + 4;        // 68: float4-aligned pad
constexpr int PLANE = TH * PS;    // 2176 words
constexpr int NCH = 4;            // channels per chunk block; LDS = 34,816 B -> 4 blocks/CU
constexpr int NCHUNK = C / NCH;   // 16
constexpr int TILES_X = W / TW, TILES_Y = H / TH;   // 7, 8
constexpr int TILES = B * TILES_X * TILES_Y;        // 448
constexpr int NT = 512;
constexpr float FMAX = (float)(R - 1);              // 7.0

// Body kept byte-compatible with the round-2 kernel (guarded atomics,
// runtime-clipped window): that variant compiles to healthy 52-VGPR code.
// Branch-free bodies consistently made hipcc emit a 12-VGPR scratch kernel.
__global__ __launch_bounds__(NT) void softsplat_gather(
    const float* __restrict__ x,
    const float* __restrict__ flow,
    const float* __restrict__ metric,
    float* __restrict__ out,      // [B, C, N] numerator
    float* __restrict__ den)      // [B, N]    denominator
{
    __shared__ float acc[NCH * PLANE];   // 34,816 B

    const int tile  = blockIdx.x;
    const int chunk = blockIdx.y;        // 0..15 = channel chunks, 16 = denominator
    const int b  = tile / (TILES_X * TILES_Y);
    const int tp = tile % (TILES_X * TILES_Y);
    const int r0 = (tp / TILES_X) * TH;
    const int c0 = (tp % TILES_X) * TW;
    const int tid = threadIdx.x;
    const bool isden = (chunk == NCHUNK);
    const int nplanes = isden ? 1 : NCH;

    for (int i = tid; i < nplanes * PLANE; i += NT) acc[i] = 0.f;
    __syncthreads();

    // halo source window, clipped to image
    const int hs0 = max(r0 - R, 0), hs1 = min(r0 + TH + R, H);
    const int ws0 = max(c0 - R, 0), ws1 = min(c0 + TW + R, W);
    const int HS = hs1 - hs0, WS = ws1 - ws0;
    const int nsrc = HS * WS;

    const float* fx_p = flow + (size_t)(b * 2 + 0) * N;
    const float* fy_p = flow + (size_t)(b * 2 + 1) * N;
    const float* m_p  = metric + (size_t)b * N;
    const float* xb   = x + ((size_t)b * C + (isden ? 0 : chunk * NCH)) * N;

    for (int s = tid; s < nsrc; s += NT) {
        const int sh = hs0 + s / WS;
        const int sw = ws0 + s % WS;
        const int sp = sh * W + sw;
        const float fdx = fx_p[sp], fdy = fy_p[sp];
        // outliers handled by the global-atomic fixup pass (exact complement predicate)
        if (fabsf(fdx) > FMAX || fabsf(fdy) > FMAX) continue;

        const float tx = (float)sw + fdx, ty = (float)sh + fdy;
        const float x0f = floorf(tx), y0f = floorf(ty);
        const int lx0 = (int)x0f - c0, ly0 = (int)y0f - r0;   // local corner coords
        const int lx1 = lx0 + 1,       ly1 = ly0 + 1;
        // tile membership == image validity (tile interior to image)
        const bool vx0 = (unsigned)lx0 < (unsigned)TW;
        const bool vx1 = (unsigned)lx1 < (unsigned)TW;
        const bool vy0 = (unsigned)ly0 < (unsigned)TH;
        const bool vy1 = (unsigned)ly1 < (unsigned)TH;
        if (!((vx0 || vx1) && (vy0 || vy1))) continue;

        const float m = __expf(m_p[sp]);
        const float fxf = tx - x0f, fyf = ty - y0f;
        const float w00 = (vx0 && vy0) ? (1.f - fxf) * (1.f - fyf) * m : 0.f;
        const float w10 = (vx1 && vy0) ? fxf * (1.f - fyf) * m : 0.f;
        const float w01 = (vx0 && vy1) ? (1.f - fxf) * fyf * m : 0.f;
        const float w11 = (vx1 && vy1) ? fxf * fyf * m : 0.f;

        const int i00 = ly0 * PS + lx0;
        const int i10 = ly0 * PS + lx1;
        const int i01 = ly1 * PS + lx0;
        const int i11 = ly1 * PS + lx1;

        if (isden) {
            if (w00 != 0.f) atomicAdd(&acc[i00], w00);
            if (w10 != 0.f) atomicAdd(&acc[i10], w10);
            if (w01 != 0.f) atomicAdd(&acc[i01], w01);
            if (w11 != 0.f) atomicAdd(&acc[i11], w11);
        } else {
            #pragma unroll
            for (int c = 0; c < NCH; ++c) {
                const float v = xb[(size_t)c * N + sp];
                float* pl = acc + c * PLANE;
                if (w00 != 0.f) atomicAdd(pl + i00, v * w00);
                if (w10 != 0.f) atomicAdd(pl + i10, v * w10);
                if (w01 != 0.f) atomicAdd(pl + i01, v * w01);
                if (w11 != 0.f) atomicAdd(pl + i11, v * w11);
            }
        }
    }
    __syncthreads();

    // non-atomic coalesced float4 writeback of the exclusive tile
    if (isden) {
        float* db = den + (size_t)b * N;
        for (int i = tid; i < TH * (TW / 4); i += NT) {
            const int yy = i / (TW / 4), xg = i % (TW / 4);
            const float* src = acc + yy * PS + xg * 4;
            *reinterpret_cast<float4*>(db + (size_t)(r0 + yy) * W + c0 + xg * 4) =
                make_float4(src[0], src[1], src[2], src[3]);
        }
    } else {
        for (int i = tid; i < NCH * TH * (TW / 4); i += NT) {
            const int c   = i / (TH * (TW / 4));
            const int rem = i % (TH * (TW / 4));
            const int yy  = rem / (TW / 4), xg = rem % (TW / 4);
            const float* src = acc + c * PLANE + yy * PS + xg * 4;
            *reinterpret_cast<float4*>(
                out + ((size_t)(b * C + chunk * NCH + c) * H + r0 + yy) * W + c0 + xg * 4) =
                make_float4(src[0], src[1], src[2], src[3]);
        }
    }
}

// Exact complement of the gather's skip predicate; global atomics on top.
__global__ __launch_bounds__(256) void softsplat_outlier(
    const float* __restrict__ x,
    const float* __restrict__ flow,
    const float* __restrict__ metric,
    float* __restrict__ out,
    float* __restrict__ den)
{
    int t = blockIdx.x * blockDim.x + threadIdx.x;
    if (t >= P) return;
    int b = t / N;
    int p = t - b * N;
    float fdx = flow[(size_t)(b * 2 + 0) * N + p];
    float fdy = flow[(size_t)(b * 2 + 1) * N + p];
    if (fabsf(fdx) <= FMAX && fabsf(fdy) <= FMAX) return;

    int h = p / W, w = p - h * W;
    float m = __expf(metric[(size_t)b * N + p]);
    float tx = (float)w + fdx, ty = (float)h + fdy;
    float x0f = floorf(tx), y0f = floorf(ty);
    int x0 = (int)x0f, y0 = (int)y0f, x1 = x0 + 1, y1 = y0 + 1;
    float fx = tx - x0f, fy = ty - y0f;
    float w00 = (1.f - fx) * (1.f - fy), w10 = fx * (1.f - fy);
    float w01 = (1.f - fx) * fy,         w11 = fx * fy;
    bool vx0 = (x0 >= 0) && (x0 < W), vx1 = (x1 >= 0) && (x1 < W);
    bool vy0 = (y0 >= 0) && (y0 < H), vy1 = (y1 >= 0) && (y1 < H);
    int cx0 = min(max(x0, 0), W - 1), cx1 = min(max(x1, 0), W - 1);
    int cy0 = min(max(y0, 0), H - 1), cy1 = min(max(y1, 0), H - 1);
    int i00 = cy0 * W + cx0, i10 = cy0 * W + cx1;
    int i01 = cy1 * W + cx0, i11 = cy1 * W + cx1;
    w00 = (vx0 && vy0) ? w00 * m : 0.f;
    w10 = (vx1 && vy0) ? w10 * m : 0.f;
    w01 = (vx0 && vy1) ? w01 * m : 0.f;
    w11 = (vx1 && vy1) ? w11 * m : 0.f;

    float* denb = den + (size_t)b * N;
    if (w00 != 0.f) atomicAdd(denb + i00, w00);
    if (w10 != 0.f) atomicAdd(denb + i10, w10);
    if (w01 != 0.f) atomicAdd(denb + i01, w01);
    if (w11 != 0.f) atomicAdd(denb + i11, w11);

    const float* xb = x + (size_t)b * C * N + p;
    float* ob = out + (size_t)b * C * N;
    for (int c = 0; c < C; ++c) {
        float v = xb[(size_t)c * N];
        float* o = ob + (size_t)c * N;
        if (w00 != 0.f) atomicAdd(o + i00, v * w00);
        if (w10 != 0.f) atomicAdd(o + i10, v * w10);
        if (w01 != 0.f) atomicAdd(o + i01, v * w01);
        if (w11 != 0.f) atomicAdd(o + i11, v * w11);
    }
}

__global__ __launch_bounds__(256) void softsplat_norm(
    float* __restrict__ out, const float* __restrict__ den)
{
    size_t t = (size_t)blockIdx.x * blockDim.x + threadIdx.x;  // one float4
    size_t e = t * 4;
    if (e >= (size_t)B * C * N) return;
    size_t b = e / ((size_t)C * N);
    size_t p = (e - b * (size_t)C * N) % N;   // N % 4 == 0

    float4 o = *reinterpret_cast<float4*>(out + e);
    const float4 d = *reinterpret_cast<const float4*>(den + b * N + p);
    o.x = o.x / (d.x + EPS);
    o.y = o.y / (d.y + EPS);
    o.z = o.z / (d.z + EPS);
    o.w = o.w / (d.w + EPS);
    *reinterpret_cast<float4*>(out + e) = o;
}

extern "C" void kernel_launch(void* const* d_in, const int* in_sizes, int n_in,
                              void* d_out, int out_size, void* d_ws, size_t ws_size,
                              hipStream_t stream) {
    const float* x      = (const float*)d_in[0];
    const float* flow   = (const float*)d_in[1];
    const float* metric = (const float*)d_in[2];
    float* out = (float*)d_out;
    float* den = (float*)d_ws;

    dim3 grid(TILES, NCHUNK + 1);   // 448 tiles x (16 channel chunks + 1 den)
    softsplat_gather<<<grid, NT, 0, stream>>>(x, flow, metric, out, den);

    softsplat_outlier<<<(P + 255) / 256, 256, 0, stream>>>(x, flow, metric, out, den);

    size_t nvec4 = (size_t)B * C * N / 4;
    softsplat_norm<<<(int)((nvec4 + 255) / 256), 256, 0, stream>>>(out, den);
}

// Round 8
// 826.082 us; speedup vs baseline: 3.1126x; 1.5777x over previous
//
#include <hip/hip_runtime.h>

#define EPS 1e-7f

constexpr int B = 8, C = 64, H = 256, W = 448;
constexpr int N = H * W;          // 114688
constexpr int P = B * N;          // 917504

constexpr int TS  = 16;           // output tile 16x16
constexpr int NT  = 256;          // one thread per output pixel
constexpr int RW  = 6;            // source-window radius (covers |flow| <= 5)
constexpr int WIN = TS + 2 * RW;  // 28
constexpr int NW  = WIN * WIN;    // 784
constexpr int K   = 12;           // per-thread list capacity (overflow: exact rescan)
constexpr int NCH = 32;           // channels per block (2 halves)
constexpr float FMAX = 5.0f;      // gather handles |flow|<=5; outlier kernel = exact complement
constexpr int TX = W / TS, TY = H / TS;   // 28, 16
constexpr int TILES = B * TX * TY;        // 3584

// Pure gather: no atomics anywhere. Each output pixel finds its covering
// sources by scanning the flow window; weights computed with arithmetic
// identical to the reference's corner weights.
__global__ __launch_bounds__(NT) void softsplat_fused(
    const float* __restrict__ x,
    const float* __restrict__ flow,
    const float* __restrict__ metric,
    float* __restrict__ out,      // [B, C, N] raw numerator
    float* __restrict__ den)      // [B, N]    denominator
{
    __shared__ float s_fx[NW], s_fy[NW], s_em[NW];   // 9,408 B
    __shared__ unsigned s_lsp[K * NT];               // 12,288 B
    __shared__ float    s_lw [K * NT];               // 12,288 B  -> 33,984 B total

    const int bid  = blockIdx.x;
    const int half = blockIdx.y;                     // 0: ch 0-31 (+den), 1: ch 32-63
    const int b   = bid / (TX * TY);
    const int tp  = bid % (TX * TY);
    const int ty0 = (tp / TX) * TS;
    const int tx0 = (tp % TX) * TS;
    const int tid = threadIdx.x;

    const float* fxg = flow + (size_t)(b * 2 + 0) * N;
    const float* fyg = flow + (size_t)(b * 2 + 1) * N;
    const float* mg  = metric + (size_t)b * N;

    // ---- stage flow/metric window; invalid or outlier sources disabled ----
    for (int i = tid; i < NW; i += NT) {
        const int wy = i / WIN, wx = i % WIN;        // compile-time divisor
        const int sh = ty0 - RW + wy, sw = tx0 - RW + wx;
        float fdx = 1.0e9f, fdy = 0.f, em = 0.f;     // sentinel: never hits
        if (sh >= 0 && sh < H && sw >= 0 && sw < W) {
            const int sp = sh * W + sw;
            const float a = fxg[sp], bb = fyg[sp];
            if (fabsf(a) <= FMAX && fabsf(bb) <= FMAX) {
                fdx = a; fdy = bb; em = __expf(mg[sp]);
            }
        }
        s_fx[i] = fdx; s_fy[i] = fdy; s_em[i] = em;
    }
    __syncthreads();

    const int qxl = tid & (TS - 1), qyl = tid >> 4;
    const int qx = tx0 + qxl, qy = ty0 + qyl;

    // ---- scan: build per-thread (sp, w) list in LDS slots ----
    int cnt = 0;
    for (int dy = -RW; dy <= RW; ++dy) {
        const int rowb = (qyl + RW + dy) * WIN + (qxl + RW);
        for (int dx = -RW; dx <= RW; ++dx) {
            const int widx = rowb + dx;
            const float fdx = s_fx[widx];
            const float tx = (float)(qx + dx) + fdx;
            const float x0f = floorf(tx);
            const int ddx = qx - (int)x0f;
            if ((unsigned)ddx > 1u) continue;
            const float fdy = s_fy[widx];
            const float tyy = (float)(qy + dy) + fdy;
            const float y0f = floorf(tyy);
            const int ddy = qy - (int)y0f;
            if ((unsigned)ddy > 1u) continue;
            const float fxf = tx - x0f, fyf = tyy - y0f;
            const float wxf = ddx ? fxf : 1.f - fxf;
            const float wyf = ddy ? fyf : 1.f - fyf;
            const float w = wxf * wyf * s_em[widx];
            if (cnt < K) {
                s_lsp[cnt * NT + tid] = (unsigned)((qy + dy) * W + (qx + dx));
                s_lw [cnt * NT + tid] = w;
            }
            cnt++;
        }
    }
    // lists are per-thread slots (written & read by same thread): no barrier needed

    // ---- channel sweep: register accumulation, no atomics ----
    const float* xb = x + ((size_t)b * C + half * NCH) * N;
    float acc[NCH];
    #pragma unroll
    for (int c = 0; c < NCH; ++c) acc[c] = 0.f;
    float dacc = 0.f;

    const int ke = min(cnt, K);
    for (int k = 0; k < ke; ++k) {
        const unsigned sp = s_lsp[k * NT + tid];
        const float w = s_lw[k * NT + tid];
        const float* xp = xb + sp;
        #pragma unroll
        for (int c = 0; c < NCH; ++c)
            acc[c] = fmaf(w, xp[(size_t)c * N], acc[c]);
        dacc += w;
    }

    // ---- exact overflow path (cnt > K: ~0.1% of pixels): rescan, skip first K ----
    if (cnt > K) {
        int seen = 0;
        for (int dy = -RW; dy <= RW; ++dy) {
            const int rowb = (qyl + RW + dy) * WIN + (qxl + RW);
            for (int dx = -RW; dx <= RW; ++dx) {
                const int widx = rowb + dx;
                const float fdx = s_fx[widx];
                const float tx = (float)(qx + dx) + fdx;
                const float x0f = floorf(tx);
                const int ddx = qx - (int)x0f;
                if ((unsigned)ddx > 1u) continue;
                const float fdy = s_fy[widx];
                const float tyy = (float)(qy + dy) + fdy;
                const float y0f = floorf(tyy);
                const int ddy = qy - (int)y0f;
                if ((unsigned)ddy > 1u) continue;
                if (seen >= K) {
                    const float fxf = tx - x0f, fyf = tyy - y0f;
                    const float wxf = ddx ? fxf : 1.f - fxf;
                    const float wyf = ddy ? fyf : 1.f - fyf;
                    const float w = wxf * wyf * s_em[widx];
                    const float* xp = xb + (qy + dy) * W + (qx + dx);
                    #pragma unroll
                    for (int c = 0; c < NCH; ++c)
                        acc[c] = fmaf(w, xp[(size_t)c * N], acc[c]);
                    dacc += w;
                }
                seen++;
            }
        }
    }

    // ---- plain coalesced writeback ----
    const int q = qy * W + qx;
    #pragma unroll
    for (int c = 0; c < NCH; ++c)
        out[((size_t)(b * C + half * NCH + c)) * N + q] = acc[c];
    if (half == 0) den[(size_t)b * N + q] = dacc;
}

// Sources with |flow|>FMAX: exact complement of the gather's predicate;
// global atomics onto the raw accumulators (runs after the fused kernel).
__global__ __launch_bounds__(256) void softsplat_outlier(
    const float* __restrict__ x,
    const float* __restrict__ flow,
    const float* __restrict__ metric,
    float* __restrict__ out,
    float* __restrict__ den)
{
    int t = blockIdx.x * blockDim.x + threadIdx.x;
    if (t >= P) return;
    int b = t / N;
    int p = t - b * N;
    float fdx = flow[(size_t)(b * 2 + 0) * N + p];
    float fdy = flow[(size_t)(b * 2 + 1) * N + p];
    if (fabsf(fdx) <= FMAX && fabsf(fdy) <= FMAX) return;

    int h = p / W, w = p - h * W;
    float m = __expf(metric[(size_t)b * N + p]);
    float tx = (float)w + fdx, ty = (float)h + fdy;
    float x0f = floorf(tx), y0f = floorf(ty);
    int x0 = (int)x0f, y0 = (int)y0f, x1 = x0 + 1, y1 = y0 + 1;
    float fx = tx - x0f, fy = ty - y0f;
    float w00 = (1.f - fx) * (1.f - fy), w10 = fx * (1.f - fy);
    float w01 = (1.f - fx) * fy,         w11 = fx * fy;
    bool vx0 = (x0 >= 0) && (x0 < W), vx1 = (x1 >= 0) && (x1 < W);
    bool vy0 = (y0 >= 0) && (y0 < H), vy1 = (y1 >= 0) && (y1 < H);
    int cx0 = min(max(x0, 0), W - 1), cx1 = min(max(x1, 0), W - 1);
    int cy0 = min(max(y0, 0), H - 1), cy1 = min(max(y1, 0), H - 1);
    int i00 = cy0 * W + cx0, i10 = cy0 * W + cx1;
    int i01 = cy1 * W + cx0, i11 = cy1 * W + cx1;
    w00 = (vx0 && vy0) ? w00 * m : 0.f;
    w10 = (vx1 && vy0) ? w10 * m : 0.f;
    w01 = (vx0 && vy1) ? w01 * m : 0.f;
    w11 = (vx1 && vy1) ? w11 * m : 0.f;

    float* denb = den + (size_t)b * N;
    if (w00 != 0.f) atomicAdd(denb + i00, w00);
    if (w10 != 0.f) atomicAdd(denb + i10, w10);
    if (w01 != 0.f) atomicAdd(denb + i01, w01);
    if (w11 != 0.f) atomicAdd(denb + i11, w11);

    const float* xb = x + (size_t)b * C * N + p;
    float* ob = out + (size_t)b * C * N;
    for (int c = 0; c < C; ++c) {
        float v = xb[(size_t)c * N];
        float* o = ob + (size_t)c * N;
        if (w00 != 0.f) atomicAdd(o + i00, v * w00);
        if (w10 != 0.f) atomicAdd(o + i10, v * w10);
        if (w01 != 0.f) atomicAdd(o + i01, v * w01);
        if (w11 != 0.f) atomicAdd(o + i11, v * w11);
    }
}

__global__ __launch_bounds__(256) void softsplat_norm(
    float* __restrict__ out, const float* __restrict__ den)
{
    size_t t = (size_t)blockIdx.x * blockDim.x + threadIdx.x;  // one float4
    size_t e = t * 4;
    if (e >= (size_t)B * C * N) return;
    size_t b = e / ((size_t)C * N);
    size_t p = (e - b * (size_t)C * N) % N;   // N % 4 == 0

    float4 o = *reinterpret_cast<float4*>(out + e);
    const float4 d = *reinterpret_cast<const float4*>(den + b * N + p);
    o.x = o.x / (d.x + EPS);
    o.y = o.y / (d.y + EPS);
    o.z = o.z / (d.z + EPS);
    o.w = o.w / (d.w + EPS);
    *reinterpret_cast<float4*>(out + e) = o;
}

extern "C" void kernel_launch(void* const* d_in, const int* in_sizes, int n_in,
                              void* d_out, int out_size, void* d_ws, size_t ws_size,
                              hipStream_t stream) {
    const float* x      = (const float*)d_in[0];
    const float* flow   = (const float*)d_in[1];
    const float* metric = (const float*)d_in[2];
    float* out = (float*)d_out;
    float* den = (float*)d_ws;

    dim3 grid(TILES, 2);   // 3584 tiles x 2 channel halves (half 0 also writes den)
    softsplat_fused<<<grid, NT, 0, stream>>>(x, flow, metric, out, den);

    softsplat_outlier<<<(P + 255) / 256, 256, 0, stream>>>(x, flow, metric, out, den);

    size_t nvec4 = (size_t)B * C * N / 4;
    softsplat_norm<<<(int)((nvec4 + 255) / 256), 256, 0, stream>>>(out, den);
}

// Round 9
// 416.022 us; speedup vs baseline: 6.1806x; 1.9857x over previous
//
#include <hip/hip_runtime.h>

#define EPS 1e-7f

constexpr int B = 8, C = 64, H = 256, W = 448;
constexpr int N = H * W;          // 114688
constexpr int P = B * N;          // 917504

constexpr int TS  = 16;           // output tile 16x16
constexpr int NT  = 256;          // one thread per output pixel
constexpr int RW  = 8;            // source-window radius (covers |flow| <= 7)
constexpr int WIN = TS + 2 * RW;  // 32
constexpr int NW  = WIN * WIN;    // 1024
constexpr int K   = 16;           // list capacity (overflow: exact in-thread rescan)
constexpr float FMAX = 7.0f;      // gather handles |flow|<=7; outlier kernel = complement
constexpr int TX = W / TS, TY = H / TS;   // 28, 16
constexpr int TILES = B * TX * TY;        // 3584
constexpr int NXCD = 8;

__device__ int g_flag;            // #source pixels with |flow|>FMAX (deterministic per input)

__global__ void zero_flag_k() { g_flag = 0; }

__global__ __launch_bounds__(256) void flag_scan(const float* __restrict__ flow)
{
    int t = blockIdx.x * blockDim.x + threadIdx.x;
    if (t >= P) return;
    int b = t / N, p = t - b * N;
    float fdx = flow[(size_t)(b * 2 + 0) * N + p];
    float fdy = flow[(size_t)(b * 2 + 1) * N + p];
    if (fabsf(fdx) > FMAX || fabsf(fdy) > FMAX) atomicAdd(&g_flag, 1);
}

// Pure gather, all 64 channels per block. If g_flag==0 (no outliers anywhere),
// writes the normalized result directly; otherwise writes raw numerator+den
// and the outlier/norm kernels finish the job.
__global__ __launch_bounds__(NT) void softsplat_fused(
    const float* __restrict__ x,
    const float* __restrict__ flow,
    const float* __restrict__ metric,
    float* __restrict__ out,      // [B, C, N]
    float* __restrict__ den)      // [B, N]
{
    __shared__ float s_fx[NW], s_fy[NW], s_em[NW];   // 12,288 B
    __shared__ unsigned s_lsp[K * NT];               // 16,384 B
    __shared__ float    s_lw [K * NT];               // 16,384 B -> 45,056 B total

    // XCD-aware swizzle: contiguous tile runs per XCD (bijective: TILES%8==0)
    int bid = blockIdx.x;
    bid = (bid % NXCD) * (TILES / NXCD) + bid / NXCD;

    const int b   = bid / (TX * TY);
    const int tp  = bid % (TX * TY);
    const int ty0 = (tp / TX) * TS;
    const int tx0 = (tp % TX) * TS;
    const int tid = threadIdx.x;

    const float* fxg = flow + (size_t)(b * 2 + 0) * N;
    const float* fyg = flow + (size_t)(b * 2 + 1) * N;
    const float* mg  = metric + (size_t)b * N;

    // ---- stage flow/metric window; OOB or outlier sources disabled via sentinel ----
    for (int i = tid; i < NW; i += NT) {
        const int wy = i / WIN, wx = i % WIN;        // WIN=32: shifts
        const int sh = ty0 - RW + wy, sw = tx0 - RW + wx;
        float fdx = 1.0e9f, fdy = 0.f, em = 0.f;     // sentinel: never matches
        if (sh >= 0 && sh < H && sw >= 0 && sw < W) {
            const int sp = sh * W + sw;
            const float a = fxg[sp], bb = fyg[sp];
            if (fabsf(a) <= FMAX && fabsf(bb) <= FMAX) {
                fdx = a; fdy = bb; em = __expf(mg[sp]);
            }
        }
        s_fx[i] = fdx; s_fy[i] = fdy; s_em[i] = em;
    }
    __syncthreads();

    const int qxl = tid & (TS - 1), qyl = tid >> 4;
    const int qx = tx0 + qxl, qy = ty0 + qyl;
    const int q  = qy * W + qx;

    // ---- scan: build per-thread (sp, w) list; dacc accumulates ALL weights ----
    int cnt = 0;
    float dacc = 0.f;
    for (int dy = -RW; dy <= RW; ++dy) {
        const int rowb = (qyl + RW + dy) * WIN + (qxl + RW);
        for (int dx = -RW; dx <= RW; ++dx) {
            const int widx = rowb + dx;
            const float fdx = s_fx[widx];
            const float tx = (float)(qx + dx) + fdx;
            const float x0f = floorf(tx);
            const int ddx = qx - (int)x0f;
            if ((unsigned)ddx > 1u) continue;
            const float fdy = s_fy[widx];
            const float tyy = (float)(qy + dy) + fdy;
            const float y0f = floorf(tyy);
            const int ddy = qy - (int)y0f;
            if ((unsigned)ddy > 1u) continue;
            const float fxf = tx - x0f, fyf = tyy - y0f;
            const float wxf = ddx ? fxf : 1.f - fxf;
            const float wyf = ddy ? fyf : 1.f - fyf;
            const float w = wxf * wyf * s_em[widx];
            if (cnt < K) {
                s_lsp[cnt * NT + tid] = (unsigned)((qy + dy) * W + (qx + dx));
                s_lw [cnt * NT + tid] = w;
            }
            cnt++;
            dacc += w;
        }
    }
    // pad remaining slots: own pixel, zero weight (harmless cached load)
    for (int j = cnt; j < K; ++j) {
        s_lsp[j * NT + tid] = (unsigned)q;
        s_lw [j * NT + tid] = 0.f;
    }

    const int flag = g_flag;
    const float rn = (flag == 0) ? 1.f / (dacc + EPS) : 1.f;

    const float* xb = x + (size_t)b * C * N;
    float* ob = out + (size_t)b * C * N + q;

    if (cnt <= K) {
        // list -> registers (static indices only)
        unsigned rsp[K]; float rw_[K];
        #pragma unroll
        for (int j = 0; j < K; ++j) {
            rsp[j] = s_lsp[j * NT + tid];
            rw_[j] = s_lw [j * NT + tid];
        }
        // c-outer sweep: per c the block touches one ~3 KB plane window (L1-resident)
        for (int c = 0; c < C; ++c) {
            const float* xp = xb + (size_t)c * N;
            float a = 0.f;
            #pragma unroll
            for (int j = 0; j < K; ++j)
                a = fmaf(rw_[j], xp[rsp[j]], a);
            ob[(size_t)c * N] = a * rn;
        }
    } else {
        // exact overflow fallback (~1e-6 of pixels): per-channel direct rescan
        for (int c = 0; c < C; ++c) {
            const float* xp = xb + (size_t)c * N;
            float a = 0.f;
            for (int dy = -RW; dy <= RW; ++dy) {
                const int rowb = (qyl + RW + dy) * WIN + (qxl + RW);
                for (int dx = -RW; dx <= RW; ++dx) {
                    const int widx = rowb + dx;
                    const float fdx = s_fx[widx];
                    const float tx = (float)(qx + dx) + fdx;
                    const float x0f = floorf(tx);
                    const int ddx = qx - (int)x0f;
                    if ((unsigned)ddx > 1u) continue;
                    const float fdy = s_fy[widx];
                    const float tyy = (float)(qy + dy) + fdy;
                    const float y0f = floorf(tyy);
                    const int ddy = qy - (int)y0f;
                    if ((unsigned)ddy > 1u) continue;
                    const float fxf = tx - x0f, fyf = tyy - y0f;
                    const float wxf = ddx ? fxf : 1.f - fxf;
                    const float wyf = ddy ? fyf : 1.f - fyf;
                    a = fmaf(wxf * wyf * s_em[widx], xp[(qy + dy) * W + (qx + dx)], a);
                }
            }
            ob[(size_t)c * N] = a * rn;
        }
    }
    den[(size_t)b * N + q] = dacc;
}

// Sources with |flow|>FMAX (exist iff g_flag!=0): global atomics onto raw accumulators.
__global__ __launch_bounds__(256) void softsplat_outlier(
    const float* __restrict__ x,
    const float* __restrict__ flow,
    const float* __restrict__ metric,
    float* __restrict__ out,
    float* __restrict__ den)
{
    int t = blockIdx.x * blockDim.x + threadIdx.x;
    if (t >= P) return;
    int b = t / N;
    int p = t - b * N;
    float fdx = flow[(size_t)(b * 2 + 0) * N + p];
    float fdy = flow[(size_t)(b * 2 + 1) * N + p];
    if (fabsf(fdx) <= FMAX && fabsf(fdy) <= FMAX) return;

    int h = p / W, w = p - h * W;
    float m = __expf(metric[(size_t)b * N + p]);
    float tx = (float)w + fdx, ty = (float)h + fdy;
    float x0f = floorf(tx), y0f = floorf(ty);
    int x0 = (int)x0f, y0 = (int)y0f, x1 = x0 + 1, y1 = y0 + 1;
    float fx = tx - x0f, fy = ty - y0f;
    float w00 = (1.f - fx) * (1.f - fy), w10 = fx * (1.f - fy);
    float w01 = (1.f - fx) * fy,         w11 = fx * fy;
    bool vx0 = (x0 >= 0) && (x0 < W), vx1 = (x1 >= 0) && (x1 < W);
    bool vy0 = (y0 >= 0) && (y0 < H), vy1 = (y1 >= 0) && (y1 < H);
    int cx0 = min(max(x0, 0), W - 1), cx1 = min(max(x1, 0), W - 1);
    int cy0 = min(max(y0, 0), H - 1), cy1 = min(max(y1, 0), H - 1);
    int i00 = cy0 * W + cx0, i10 = cy0 * W + cx1;
    int i01 = cy1 * W + cx0, i11 = cy1 * W + cx1;
    w00 = (vx0 && vy0) ? w00 * m : 0.f;
    w10 = (vx1 && vy0) ? w10 * m : 0.f;
    w01 = (vx0 && vy1) ? w01 * m : 0.f;
    w11 = (vx1 && vy1) ? w11 * m : 0.f;

    float* denb = den + (size_t)b * N;
    if (w00 != 0.f) atomicAdd(denb + i00, w00);
    if (w10 != 0.f) atomicAdd(denb + i10, w10);
    if (w01 != 0.f) atomicAdd(denb + i01, w01);
    if (w11 != 0.f) atomicAdd(denb + i11, w11);

    const float* xb = x + (size_t)b * C * N + p;
    float* ob = out + (size_t)b * C * N;
    for (int c = 0; c < C; ++c) {
        float v = xb[(size_t)c * N];
        float* o = ob + (size_t)c * N;
        if (w00 != 0.f) atomicAdd(o + i00, v * w00);
        if (w10 != 0.f) atomicAdd(o + i10, v * w10);
        if (w01 != 0.f) atomicAdd(o + i01, v * w01);
        if (w11 != 0.f) atomicAdd(o + i11, v * w11);
    }
}

// Runs only when outliers exist (g_flag!=0); otherwise exits immediately.
__global__ __launch_bounds__(256) void softsplat_norm(
    float* __restrict__ out, const float* __restrict__ den)
{
    if (g_flag == 0) return;   // fused already normalized
    size_t t = (size_t)blockIdx.x * blockDim.x + threadIdx.x;  // one float4
    size_t e = t * 4;
    if (e >= (size_t)B * C * N) return;
    size_t b = e / ((size_t)C * N);
    size_t p = (e - b * (size_t)C * N) % N;   // N % 4 == 0

    float4 o = *reinterpret_cast<float4*>(out + e);
    const float4 d = *reinterpret_cast<const float4*>(den + b * N + p);
    o.x = o.x / (d.x + EPS);
    o.y = o.y / (d.y + EPS);
    o.z = o.z / (d.z + EPS);
    o.w = o.w / (d.w + EPS);
    *reinterpret_cast<float4*>(out + e) = o;
}

extern "C" void kernel_launch(void* const* d_in, const int* in_sizes, int n_in,
                              void* d_out, int out_size, void* d_ws, size_t ws_size,
                              hipStream_t stream) {
    const float* x      = (const float*)d_in[0];
    const float* flow   = (const float*)d_in[1];
    const float* metric = (const float*)d_in[2];
    float* out = (float*)d_out;
    float* den = (float*)d_ws;

    zero_flag_k<<<1, 1, 0, stream>>>();
    flag_scan<<<(P + 255) / 256, 256, 0, stream>>>(flow);

    softsplat_fused<<<TILES, NT, 0, stream>>>(x, flow, metric, out, den);

    softsplat_outlier<<<(P + 255) / 256, 256, 0, stream>>>(x, flow, metric, out, den);

    size_t nvec4 = (size_t)B * C * N / 4;
    softsplat_norm<<<(int)((nvec4 + 255) / 256), 256, 0, stream>>>(out, den);
}

// Round 10
// 386.910 us; speedup vs baseline: 6.6456x; 1.0752x over previous
//
#include <hip/hip_runtime.h>

#define EPS 1e-7f

constexpr int B = 8, C = 64, H = 256, W = 448;
constexpr int N = H * W;          // 114688
constexpr int P = B * N;          // 917504

constexpr int TS  = 16;           // output tile 16x16
constexpr int NT  = 256;          // one thread per output pixel
constexpr int RW  = 8;            // source-window radius (covers |flow| <= 7)
constexpr int WIN = 32;           // TS + 2*RW
constexpr int NW  = WIN * WIN;    // 1024
constexpr int SW  = WIN + 1;      // 33: staged x stride (diagonal bank spread)
constexpr int NWS = WIN * SW;     // 1056 words per channel
constexpr int K   = 20;           // list capacity; P(cnt>20)~1e-9/px (exact fallback kept)
constexpr int CHB = 4;            // channels per staged chunk
constexpr int NCHUNK = C / CHB;   // 16
constexpr float FMAX = 7.0f;
constexpr int TX = W / TS, TY = H / TS;   // 28, 16
constexpr int TILES = B * TX * TY;        // 3584
constexpr int NXCD = 8;

// LDS word offsets. Phase 1: flow/metric window + per-thread lists.
// Phase 2 (after lists -> registers): same memory reused as x staging buffers.
constexpr int L_FX = 0, L_FY = 1024, L_EM = 2048, L_W = 3072;
constexpr int L_SP = L_W + K * NT;                 // 8192
constexpr int LDS_WORDS_P1 = L_SP + K * NT;        // 13312
constexpr int LDS_WORDS_P2 = 2 * CHB * NWS;        // 8448
constexpr int LDS_WORDS = LDS_WORDS_P1 > LDS_WORDS_P2 ? LDS_WORDS_P1 : LDS_WORDS_P2;
// 13312 words = 53,248 B -> exactly 3 blocks/CU (159,744 <= 163,840)

__device__ int g_flag;            // #sources with |flow|>FMAX (deterministic per input)

__global__ void zero_flag_k() { g_flag = 0; }

__global__ __launch_bounds__(256) void flag_scan(const float* __restrict__ flow)
{
    int t = blockIdx.x * blockDim.x + threadIdx.x;
    if (t >= P) return;
    int b = t / N, p = t - b * N;
    float fdx = flow[(size_t)(b * 2 + 0) * N + p];
    float fdy = flow[(size_t)(b * 2 + 1) * N + p];
    if (fabsf(fdx) > FMAX || fabsf(fdy) > FMAX) atomicAdd(&g_flag, 1);
}

#define STAGE_LOAD(gg)                                                        \
    {                                                                         \
        const int cbase = (gg) * CHB;                                         \
        _Pragma("unroll")                                                     \
        for (int k2 = 0; k2 < 16; ++k2) {                                     \
            const int i   = tid + k2 * NT;                                    \
            const int cl  = i >> 10;                                          \
            const int pos = i & 1023;                                         \
            const int row = pos >> 5, col = pos & 31;                         \
            const int sh = ty0 - RW + row, sw2 = tx0 - RW + col;              \
            const bool v = (sh >= 0) & (sh < H) & (sw2 >= 0) & (sw2 < W);     \
            sreg[k2] = v ? xb[(size_t)(cbase + cl) * N + sh * W + sw2] : 0.f; \
        }                                                                     \
    }

#define STAGE_WRITE(bufp)                                                     \
    {                                                                         \
        _Pragma("unroll")                                                     \
        for (int k2 = 0; k2 < 16; ++k2) {                                     \
            const int i   = tid + k2 * NT;                                    \
            const int cl  = i >> 10;                                          \
            const int pos = i & 1023;                                         \
            const int row = pos >> 5, col = pos & 31;                         \
            (bufp)[cl * NWS + row * SW + col] = sreg[k2];                     \
        }                                                                     \
    }

__global__ __launch_bounds__(NT) void softsplat_fused(
    const float* __restrict__ x,
    const float* __restrict__ flow,
    const float* __restrict__ metric,
    float* __restrict__ out,      // [B, C, N]
    float* __restrict__ den)      // [B, N]
{
    __shared__ float lds[LDS_WORDS];
    float*    s_fx  = lds + L_FX;
    float*    s_fy  = lds + L_FY;
    float*    s_em  = lds + L_EM;
    float*    s_lw  = lds + L_W;
    unsigned* s_lsp = (unsigned*)(lds + L_SP);

    // XCD-aware bijective swizzle (TILES % 8 == 0)
    int bid = blockIdx.x;
    bid = (bid % NXCD) * (TILES / NXCD) + bid / NXCD;

    const int b   = bid / (TX * TY);
    const int tp  = bid % (TX * TY);
    const int ty0 = (tp / TX) * TS;
    const int tx0 = (tp % TX) * TS;
    const int tid = threadIdx.x;

    const float* fxg = flow + (size_t)(b * 2 + 0) * N;
    const float* fyg = flow + (size_t)(b * 2 + 1) * N;
    const float* mg  = metric + (size_t)b * N;

    // ---- phase 1a: stage flow/metric window (sentinel disables OOB/outlier) ----
    for (int i = tid; i < NW; i += NT) {
        const int wy = i >> 5, wx = i & 31;
        const int sh = ty0 - RW + wy, sw = tx0 - RW + wx;
        float fdx = 1.0e9f, fdy = 0.f, em = 0.f;
        if (sh >= 0 && sh < H && sw >= 0 && sw < W) {
            const int sp = sh * W + sw;
            const float a = fxg[sp], bb = fyg[sp];
            if (fabsf(a) <= FMAX && fabsf(bb) <= FMAX) {
                fdx = a; fdy = bb; em = __expf(mg[sp]);
            }
        }
        s_fx[i] = fdx; s_fy[i] = fdy; s_em[i] = em;
    }
    __syncthreads();

    const int qxl = tid & (TS - 1), qyl = tid >> 4;
    const int qx = tx0 + qxl, qy = ty0 + qyl;
    const int q  = qy * W + qx;

    // ---- phase 1b: scan -> per-thread (local idx, w) list; dacc = all weights ----
    int cnt = 0;
    float dacc = 0.f;
    for (int dy = -RW; dy <= RW; ++dy) {
        const int lrow = qyl + RW + dy;
        const int rowb = lrow * WIN + (qxl + RW);
        for (int dx = -RW; dx <= RW; ++dx) {
            const int widx = rowb + dx;
            const float fdx = s_fx[widx];
            const float tx = (float)(qx + dx) + fdx;
            const float x0f = floorf(tx);
            const int ddx = qx - (int)x0f;
            if ((unsigned)ddx > 1u) continue;
            const float fdy = s_fy[widx];
            const float tyy = (float)(qy + dy) + fdy;
            const float y0f = floorf(tyy);
            const int ddy = qy - (int)y0f;
            if ((unsigned)ddy > 1u) continue;
            const float fxf = tx - x0f, fyf = tyy - y0f;
            const float wxf = ddx ? fxf : 1.f - fxf;
            const float wyf = ddy ? fyf : 1.f - fyf;
            const float w = wxf * wyf * s_em[widx];
            if (cnt < K) {
                s_lsp[cnt * NT + tid] = (unsigned)(widx + lrow);  // stride-33 index
                s_lw [cnt * NT + tid] = w;
            }
            cnt++;
            dacc += w;
        }
    }
    for (int j = cnt; j < K; ++j) {                 // pad: own center, zero weight
        s_lsp[j * NT + tid] = (unsigned)((qyl + RW) * SW + (qxl + RW));
        s_lw [j * NT + tid] = 0.f;
    }

    // wave-uniform loop bound: max cnt over the wave (SGPR -> scalar branch)
    int km = cnt;
    #pragma unroll
    for (int m = 1; m < 64; m <<= 1) km = max(km, __shfl_xor(km, m));
    const int kwave = min(K, __builtin_amdgcn_readfirstlane(km));

    const int flag = g_flag;
    const float rn = (flag == 0) ? 1.f / (dacc + EPS) : 1.f;

    const float* xb = x + (size_t)b * C * N;
    float* ob = out + (size_t)b * C * N + q;
    den[(size_t)b * N + q] = dacc;

    // list -> registers (static indices only)
    unsigned rsp[K]; float rw_[K];
    #pragma unroll
    for (int j = 0; j < K; ++j) {
        rsp[j] = s_lsp[j * NT + tid];
        rw_[j] = s_lw [j * NT + tid];
    }

    // ---- phase 1c: exact overflow fallback (statistically never) ----
    const bool ovf = (cnt > K);
    if (ovf) {
        for (int c = 0; c < C; ++c) {
            const float* xp = xb + (size_t)c * N;
            float a = 0.f;
            for (int dy = -RW; dy <= RW; ++dy) {
                const int rowb = (qyl + RW + dy) * WIN + (qxl + RW);
                for (int dx = -RW; dx <= RW; ++dx) {
                    const int widx = rowb + dx;
                    const float fdx = s_fx[widx];
                    const float tx = (float)(qx + dx) + fdx;
                    const float x0f = floorf(tx);
                    const int ddx = qx - (int)x0f;
                    if ((unsigned)ddx > 1u) continue;
                    const float fdy = s_fy[widx];
                    const float tyy = (float)(qy + dy) + fdy;
                    const float y0f = floorf(tyy);
                    const int ddy = qy - (int)y0f;
                    if ((unsigned)ddy > 1u) continue;
                    const float fxf = tx - x0f, fyf = tyy - y0f;
                    const float wxf = ddx ? fxf : 1.f - fxf;
                    const float wyf = ddy ? fyf : 1.f - fyf;
                    a = fmaf(wxf * wyf * s_em[widx], xp[(qy + dy) * W + (qx + dx)], a);
                }
            }
            ob[(size_t)c * N] = a * rn;
        }
    }
    __syncthreads();   // phase-1 LDS released; reuse as staging buffers

    // ---- phase 2: double-buffered LDS x-staging, ds_read gathers ----
    float sreg[16];
    STAGE_LOAD(0)
    STAGE_WRITE(lds)
    __syncthreads();
    for (int g = 0; g < NCHUNK; ++g) {
        float* bufc = lds + (g & 1) * (CHB * NWS);
        float* bufn = lds + ((g & 1) ^ 1) * (CHB * NWS);
        if (g + 1 < NCHUNK) STAGE_LOAD(g + 1)   // issue early (T14): hides HBM latency
        #pragma unroll
        for (int cl = 0; cl < CHB; ++cl) {
            const float* bc = bufc + cl * NWS;
            float a = 0.f;
            #pragma unroll
            for (int j = 0; j < K; ++j) {
                if (j >= kwave) break;          // wave-uniform scalar branch
                a = fmaf(rw_[j], bc[rsp[j]], a);
            }
            if (!ovf) ob[(size_t)(g * CHB + cl) * N] = a * rn;
        }
        if (g + 1 < NCHUNK) STAGE_WRITE(bufn)   // write late, after compute
        __syncthreads();
    }
}

// Sources with |flow|>FMAX (exist iff g_flag!=0): global atomics onto raw accumulators.
__global__ __launch_bounds__(256) void softsplat_outlier(
    const float* __restrict__ x,
    const float* __restrict__ flow,
    const float* __restrict__ metric,
    float* __restrict__ out,
    float* __restrict__ den)
{
    int t = blockIdx.x * blockDim.x + threadIdx.x;
    if (t >= P) return;
    int b = t / N;
    int p = t - b * N;
    float fdx = flow[(size_t)(b * 2 + 0) * N + p];
    float fdy = flow[(size_t)(b * 2 + 1) * N + p];
    if (fabsf(fdx) <= FMAX && fabsf(fdy) <= FMAX) return;

    int h = p / W, w = p - h * W;
    float m = __expf(metric[(size_t)b * N + p]);
    float tx = (float)w + fdx, ty = (float)h + fdy;
    float x0f = floorf(tx), y0f = floorf(ty);
    int x0 = (int)x0f, y0 = (int)y0f, x1 = x0 + 1, y1 = y0 + 1;
    float fx = tx - x0f, fy = ty - y0f;
    float w00 = (1.f - fx) * (1.f - fy), w10 = fx * (1.f - fy);
    float w01 = (1.f - fx) * fy,         w11 = fx * fy;
    bool vx0 = (x0 >= 0) && (x0 < W), vx1 = (x1 >= 0) && (x1 < W);
    bool vy0 = (y0 >= 0) && (y0 < H), vy1 = (y1 >= 0) && (y1 < H);
    int cx0 = min(max(x0, 0), W - 1), cx1 = min(max(x1, 0), W - 1);
    int cy0 = min(max(y0, 0), H - 1), cy1 = min(max(y1, 0), H - 1);
    int i00 = cy0 * W + cx0, i10 = cy0 * W + cx1;
    int i01 = cy1 * W + cx0, i11 = cy1 * W + cx1;
    w00 = (vx0 && vy0) ? w00 * m : 0.f;
    w10 = (vx1 && vy0) ? w10 * m : 0.f;
    w01 = (vx0 && vy1) ? w01 * m : 0.f;
    w11 = (vx1 && vy1) ? w11 * m : 0.f;

    float* denb = den + (size_t)b * N;
    if (w00 != 0.f) atomicAdd(denb + i00, w00);
    if (w10 != 0.f) atomicAdd(denb + i10, w10);
    if (w01 != 0.f) atomicAdd(denb + i01, w01);
    if (w11 != 0.f) atomicAdd(denb + i11, w11);

    const float* xb = x + (size_t)b * C * N + p;
    float* ob = out + (size_t)b * C * N;
    for (int c = 0; c < C; ++c) {
        float v = xb[(size_t)c * N];
        float* o = ob + (size_t)c * N;
        if (w00 != 0.f) atomicAdd(o + i00, v * w00);
        if (w10 != 0.f) atomicAdd(o + i10, v * w10);
        if (w01 != 0.f) atomicAdd(o + i01, v * w01);
        if (w11 != 0.f) atomicAdd(o + i11, v * w11);
    }
}

// Runs only when outliers exist (g_flag!=0); otherwise fused already normalized.
__global__ __launch_bounds__(256) void softsplat_norm(
    float* __restrict__ out, const float* __restrict__ den)
{
    if (g_flag == 0) return;
    size_t t = (size_t)blockIdx.x * blockDim.x + threadIdx.x;  // one float4
    size_t e = t * 4;
    if (e >= (size_t)B * C * N) return;
    size_t b = e / ((size_t)C * N);
    size_t p = (e - b * (size_t)C * N) % N;   // N % 4 == 0

    float4 o = *reinterpret_cast<float4*>(out + e);
    const float4 d = *reinterpret_cast<const float4*>(den + b * N + p);
    o.x = o.x / (d.x + EPS);
    o.y = o.y / (d.y + EPS);
    o.z = o.z / (d.z + EPS);
    o.w = o.w / (d.w + EPS);
    *reinterpret_cast<float4*>(out + e) = o;
}

extern "C" void kernel_launch(void* const* d_in, const int* in_sizes, int n_in,
                              void* d_out, int out_size, void* d_ws, size_t ws_size,
                              hipStream_t stream) {
    const float* x      = (const float*)d_in[0];
    const float* flow   = (const float*)d_in[1];
    const float* metric = (const float*)d_in[2];
    float* out = (float*)d_out;
    float* den = (float*)d_ws;

    zero_flag_k<<<1, 1, 0, stream>>>();
    flag_scan<<<(P + 255) / 256, 256, 0, stream>>>(flow);

    softsplat_fused<<<TILES, NT, 0, stream>>>(x, flow, metric, out, den);

    softsplat_outlier<<<(P + 255) / 256, 256, 0, stream>>>(x, flow, metric, out, den);

    size_t nvec4 = (size_t)B * C * N / 4;
    softsplat_norm<<<(int)((nvec4 + 255) / 256), 256, 0, stream>>>(out, den);
}

// Round 11
// 326.943 us; speedup vs baseline: 7.8645x; 1.1834x over previous
//
#include <hip/hip_runtime.h>

#define EPS 1e-7f

constexpr int B = 8, C = 64, H = 256, W = 448;
constexpr int N = H * W;          // 114688
constexpr int P = B * N;          // 917504

constexpr int TS  = 16;           // output tile 16x16
constexpr int NT  = 256;          // one thread per output pixel
constexpr int RW  = 8;            // max source radius (covers |flow| <= 7)
constexpr int WIN = 32;           // TS + 2*RW
constexpr int NW  = WIN * WIN;    // 1024
constexpr int SW  = 36;           // staged-x stride: 16B-aligned rows, bank rotation by 4
constexpr int NWS = WIN * SW;     // 1152 words per channel plane
constexpr int K   = 20;           // list capacity; P(cnt>20)~1e-9/px (exact fallback kept)
constexpr int CHB = 4;            // channels per staged chunk
constexpr int NCHUNK = C / CHB;   // 16
constexpr float FMAX = 7.0f;
constexpr int TX = W / TS, TY = H / TS;   // 28, 16
constexpr int TILES = B * TX * TY;        // 3584
constexpr int NXCD = 8;

// Phase-1 layout: s_fx[1024] s_fy[1024] s_em[1024] s_pk[K*256=5120] -> 8192 words
// Phase-2 layout: two x-staging buffers, 2 * CHB * NWS = 9216 words (reuses all of it)
constexpr int L_FX = 0, L_FY = 1024, L_EM = 2048, L_PK = 3072;
constexpr int LDS_WORDS = 2 * CHB * NWS;   // 9216 words = 36,864 B -> 4 blocks/CU

__device__ int g_flag;            // #sources with |flow|>FMAX (deterministic per input)

__global__ void zero_flag_k() { g_flag = 0; }

__global__ __launch_bounds__(256) void flag_scan(const float* __restrict__ flow)
{
    int t = blockIdx.x * blockDim.x + threadIdx.x;
    if (t >= P) return;
    int b = t / N, p = t - b * N;
    float fdx = flow[(size_t)(b * 2 + 0) * N + p];
    float fdy = flow[(size_t)(b * 2 + 1) * N + p];
    if (fabsf(fdx) > FMAX || fabsf(fdy) > FMAX) atomicAdd(&g_flag, 1);
}

// float4 staging: all addresses 16B-aligned (W,N ≡ 0 mod 4; tx0-RW ≡ 0 mod 4;
// OOB float4s are fully in or fully out per axis -> whole-vector predicate).
#define STAGE_LOAD(gg)                                                        \
    {                                                                         \
        const int cbase = (gg) * CHB;                                         \
        _Pragma("unroll")                                                     \
        for (int k2 = 0; k2 < 4; ++k2) {                                      \
            const int i   = tid + k2 * NT;                                    \
            const int cl  = i >> 8;                                           \
            const int pos = i & 255;                                          \
            const int row = pos >> 3, c4 = pos & 7;                           \
            const int sh = ty0 - RW + row;                                    \
            const int sc = tx0 - RW + c4 * 4;                                 \
            const bool v = (sh >= 0) & (sh < H) & (sc >= 0) & (sc < W);       \
            sreg[k2] = v ? *(const float4*)(xb + (size_t)(cbase + cl) * N +   \
                                            sh * W + sc)                      \
                         : make_float4(0.f, 0.f, 0.f, 0.f);                   \
        }                                                                     \
    }

#define STAGE_WRITE(bufp)                                                     \
    {                                                                         \
        _Pragma("unroll")                                                     \
        for (int k2 = 0; k2 < 4; ++k2) {                                      \
            const int i   = tid + k2 * NT;                                    \
            const int cl  = i >> 8;                                           \
            const int pos = i & 255;                                          \
            const int row = pos >> 3, c4 = pos & 7;                           \
            *(float4*)((bufp) + cl * NWS + row * SW + c4 * 4) = sreg[k2];     \
        }                                                                     \
    }

__global__ __launch_bounds__(NT) void softsplat_fused(
    const float* __restrict__ x,
    const float* __restrict__ flow,
    const float* __restrict__ metric,
    float* __restrict__ out,      // [B, C, N]
    float* __restrict__ den)      // [B, N]
{
    __shared__ float lds[LDS_WORDS];
    __shared__ float s_max[4];                       // per-wave |flow| maxima
    float*    s_fx = lds + L_FX;
    float*    s_fy = lds + L_FY;
    float*    s_em = lds + L_EM;
    unsigned* s_pk = (unsigned*)(lds + L_PK);        // packed (w_hi21 | widx11)

    // XCD-aware bijective swizzle (TILES % 8 == 0)
    int bid = blockIdx.x;
    bid = (bid % NXCD) * (TILES / NXCD) + bid / NXCD;

    const int b   = bid / (TX * TY);
    const int tp  = bid % (TX * TY);
    const int ty0 = (tp / TX) * TS;
    const int tx0 = (tp % TX) * TS;
    const int tid = threadIdx.x;

    const float* fxg = flow + (size_t)(b * 2 + 0) * N;
    const float* fyg = flow + (size_t)(b * 2 + 1) * N;
    const float* mg  = metric + (size_t)b * N;

    // ---- phase 1a: stage flow/metric window; track valid |flow| max ----
    float mymax = 0.f;
    for (int i = tid; i < NW; i += NT) {
        const int wy = i >> 5, wx = i & 31;
        const int sh = ty0 - RW + wy, sw = tx0 - RW + wx;
        float fdx = 1.0e9f, fdy = 0.f, em = 0.f;
        if (sh >= 0 && sh < H && sw >= 0 && sw < W) {
            const int sp = sh * W + sw;
            const float a = fxg[sp], bb = fyg[sp];
            if (fabsf(a) <= FMAX && fabsf(bb) <= FMAX) {
                fdx = a; fdy = bb; em = __expf(mg[sp]);
                mymax = fmaxf(mymax, fmaxf(fabsf(a), fabsf(bb)));
            }
        }
        s_fx[i] = fdx; s_fy[i] = fdy; s_em[i] = em;
    }
    // block max -> exact dynamic scan radius (source at offset d needs |flow| >= d-1)
    #pragma unroll
    for (int m = 1; m < 64; m <<= 1) mymax = fmaxf(mymax, __shfl_xor(mymax, m));
    if ((tid & 63) == 0) s_max[tid >> 6] = mymax;
    __syncthreads();
    const float M = fmaxf(fmaxf(s_max[0], s_max[1]), fmaxf(s_max[2], s_max[3]));
    const int Rdyn = min(RW, (int)M + 1);

    const int qxl = tid & (TS - 1), qyl = tid >> 4;
    const int qx = tx0 + qxl, qy = ty0 + qyl;
    const int q  = qy * W + qx;

    // ---- phase 1b: scan [-Rdyn,Rdyn]^2 -> packed per-thread list ----
    int cnt = 0;
    float dacc = 0.f;
    for (int dy = -Rdyn; dy <= Rdyn; ++dy) {
        const int lrow = qyl + RW + dy;
        const int rowb = lrow * WIN + (qxl + RW);
        for (int dx = -Rdyn; dx <= Rdyn; ++dx) {
            const int widx = rowb + dx;
            const float fdx = s_fx[widx];
            const float tx = (float)(qx + dx) + fdx;
            const float x0f = floorf(tx);
            const int ddx = qx - (int)x0f;
            if ((unsigned)ddx > 1u) continue;
            const float fdy = s_fy[widx];
            const float tyy = (float)(qy + dy) + fdy;
            const float y0f = floorf(tyy);
            const int ddy = qy - (int)y0f;
            if ((unsigned)ddy > 1u) continue;
            const float fxf = tx - x0f, fyf = tyy - y0f;
            const float wxf = ddx ? fxf : 1.f - fxf;
            const float wyf = ddy ? fyf : 1.f - fyf;
            const float w = wxf * wyf * s_em[widx];
            if (cnt < K) {
                // pack gather index (stride-36 layout, <=1147 -> 11 bits) into w's low mantissa
                const unsigned gidx = (unsigned)(lrow * SW + (qxl + RW + dx));
                s_pk[cnt * NT + tid] = (__float_as_uint(w) & 0xFFFFF800u) | gidx;
            }
            cnt++;
            dacc += w;   // full-precision denominator
        }
    }
    for (int j = cnt; j < K; ++j)
        s_pk[j * NT + tid] = (unsigned)((qyl + RW) * SW + (qxl + RW));  // w=0 pad

    // wave-uniform loop bound
    int km = cnt;
    #pragma unroll
    for (int m = 1; m < 64; m <<= 1) km = max(km, __shfl_xor(km, m));
    const int kwave = min(K, __builtin_amdgcn_readfirstlane(km));

    const int flag = g_flag;
    const float rn = (flag == 0) ? 1.f / (dacc + EPS) : 1.f;

    const float* xb = x + (size_t)b * C * N;
    float* ob = out + (size_t)b * C * N + q;
    den[(size_t)b * N + q] = dacc;

    // list -> registers (static indices only)
    unsigned rsp[K]; float rw_[K];
    #pragma unroll
    for (int j = 0; j < K; ++j) {
        const unsigned pk = s_pk[j * NT + tid];
        rsp[j] = pk & 0x7FFu;
        rw_[j] = __uint_as_float(pk & 0xFFFFF800u);
    }

    // ---- phase 1c: exact overflow fallback (statistically never) ----
    const bool ovf = (cnt > K);
    if (ovf) {
        for (int c = 0; c < C; ++c) {
            const float* xp = xb + (size_t)c * N;
            float a = 0.f;
            for (int dy = -Rdyn; dy <= Rdyn; ++dy) {
                const int rowb = (qyl + RW + dy) * WIN + (qxl + RW);
                for (int dx = -Rdyn; dx <= Rdyn; ++dx) {
                    const int widx = rowb + dx;
                    const float fdx = s_fx[widx];
                    const float tx = (float)(qx + dx) + fdx;
                    const float x0f = floorf(tx);
                    const int ddx = qx - (int)x0f;
                    if ((unsigned)ddx > 1u) continue;
                    const float fdy = s_fy[widx];
                    const float tyy = (float)(qy + dy) + fdy;
                    const float y0f = floorf(tyy);
                    const int ddy = qy - (int)y0f;
                    if ((unsigned)ddy > 1u) continue;
                    const float fxf = tx - x0f, fyf = tyy - y0f;
                    const float wxf = ddx ? fxf : 1.f - fxf;
                    const float wyf = ddy ? fyf : 1.f - fyf;
                    a = fmaf(wxf * wyf * s_em[widx], xp[(qy + dy) * W + (qx + dx)], a);
                }
            }
            ob[(size_t)c * N] = a * rn;
        }
    }
    __syncthreads();   // phase-1 LDS released; reuse as staging buffers

    // ---- phase 2: double-buffered LDS x-staging (float4), ds_read gathers ----
    float4 sreg[4];
    STAGE_LOAD(0)
    STAGE_WRITE(lds)
    __syncthreads();
    for (int g = 0; g < NCHUNK; ++g) {
        float* bufc = lds + (g & 1) * (CHB * NWS);
        float* bufn = lds + ((g & 1) ^ 1) * (CHB * NWS);
        if (g + 1 < NCHUNK) STAGE_LOAD(g + 1)   // issue early: HBM latency under compute
        #pragma unroll
        for (int cl = 0; cl < CHB; ++cl) {
            const float* bc = bufc + cl * NWS;
            float a = 0.f;
            #pragma unroll
            for (int j = 0; j < K; ++j) {
                if (j >= kwave) break;          // wave-uniform scalar branch
                a = fmaf(rw_[j], bc[rsp[j]], a);
            }
            if (!ovf) ob[(size_t)(g * CHB + cl) * N] = a * rn;
        }
        if (g + 1 < NCHUNK) STAGE_WRITE(bufn)   // write late, after compute
        __syncthreads();
    }
}

// Sources with |flow|>FMAX (exist iff g_flag!=0): global atomics onto raw accumulators.
__global__ __launch_bounds__(256) void softsplat_outlier(
    const float* __restrict__ x,
    const float* __restrict__ flow,
    const float* __restrict__ metric,
    float* __restrict__ out,
    float* __restrict__ den)
{
    int t = blockIdx.x * blockDim.x + threadIdx.x;
    if (t >= P) return;
    int b = t / N;
    int p = t - b * N;
    float fdx = flow[(size_t)(b * 2 + 0) * N + p];
    float fdy = flow[(size_t)(b * 2 + 1) * N + p];
    if (fabsf(fdx) <= FMAX && fabsf(fdy) <= FMAX) return;

    int h = p / W, w = p - h * W;
    float m = __expf(metric[(size_t)b * N + p]);
    float tx = (float)w + fdx, ty = (float)h + fdy;
    float x0f = floorf(tx), y0f = floorf(ty);
    int x0 = (int)x0f, y0 = (int)y0f, x1 = x0 + 1, y1 = y0 + 1;
    float fx = tx - x0f, fy = ty - y0f;
    float w00 = (1.f - fx) * (1.f - fy), w10 = fx * (1.f - fy);
    float w01 = (1.f - fx) * fy,         w11 = fx * fy;
    bool vx0 = (x0 >= 0) && (x0 < W), vx1 = (x1 >= 0) && (x1 < W);
    bool vy0 = (y0 >= 0) && (y0 < H), vy1 = (y1 >= 0) && (y1 < H);
    int cx0 = min(max(x0, 0), W - 1), cx1 = min(max(x1, 0), W - 1);
    int cy0 = min(max(y0, 0), H - 1), cy1 = min(max(y1, 0), H - 1);
    int i00 = cy0 * W + cx0, i10 = cy0 * W + cx1;
    int i01 = cy1 * W + cx0, i11 = cy1 * W + cx1;
    w00 = (vx0 && vy0) ? w00 * m : 0.f;
    w10 = (vx1 && vy0) ? w10 * m : 0.f;
    w01 = (vx0 && vy1) ? w01 * m : 0.f;
    w11 = (vx1 && vy1) ? w11 * m : 0.f;

    float* denb = den + (size_t)b * N;
    if (w00 != 0.f) atomicAdd(denb + i00, w00);
    if (w10 != 0.f) atomicAdd(denb + i10, w10);
    if (w01 != 0.f) atomicAdd(denb + i01, w01);
    if (w11 != 0.f) atomicAdd(denb + i11, w11);

    const float* xb = x + (size_t)b * C * N + p;
    float* ob = out + (size_t)b * C * N;
    for (int c = 0; c < C; ++c) {
        float v = xb[(size_t)c * N];
        float* o = ob + (size_t)c * N;
        if (w00 != 0.f) atomicAdd(o + i00, v * w00);
        if (w10 != 0.f) atomicAdd(o + i10, v * w10);
        if (w01 != 0.f) atomicAdd(o + i01, v * w01);
        if (w11 != 0.f) atomicAdd(o + i11, v * w11);
    }
}

// Runs only when outliers exist (g_flag!=0); otherwise fused already normalized.
__global__ __launch_bounds__(256) void softsplat_norm(
    float* __restrict__ out, const float* __restrict__ den)
{
    if (g_flag == 0) return;
    size_t t = (size_t)blockIdx.x * blockDim.x + threadIdx.x;  // one float4
    size_t e = t * 4;
    if (e >= (size_t)B * C * N) return;
    size_t b = e / ((size_t)C * N);
    size_t p = (e - b * (size_t)C * N) % N;   // N % 4 == 0

    float4 o = *reinterpret_cast<float4*>(out + e);
    const float4 d = *reinterpret_cast<const float4*>(den + b * N + p);
    o.x = o.x / (d.x + EPS);
    o.y = o.y / (d.y + EPS);
    o.z = o.z / (d.z + EPS);
    o.w = o.w / (d.w + EPS);
    *reinterpret_cast<float4*>(out + e) = o;
}

extern "C" void kernel_launch(void* const* d_in, const int* in_sizes, int n_in,
                              void* d_out, int out_size, void* d_ws, size_t ws_size,
                              hipStream_t stream) {
    const float* x      = (const float*)d_in[0];
    const float* flow   = (const float*)d_in[1];
    const float* metric = (const float*)d_in[2];
    float* out = (float*)d_out;
    float* den = (float*)d_ws;

    zero_flag_k<<<1, 1, 0, stream>>>();
    flag_scan<<<(P + 255) / 256, 256, 0, stream>>>(flow);

    softsplat_fused<<<TILES, NT, 0, stream>>>(x, flow, metric, out, den);

    softsplat_outlier<<<(P + 255) / 256, 256, 0, stream>>>(x, flow, metric, out, den);

    size_t nvec4 = (size_t)B * C * N / 4;
    softsplat_norm<<<(int)((nvec4 + 255) / 256), 256, 0, stream>>>(out, den);
}

// Round 13
// 251.436 us; speedup vs baseline: 10.2263x; 1.3003x over previous
//
#include <hip/hip_runtime.h>

#define EPS 1e-7f

constexpr int B = 8, C = 64, H = 256, W = 448;
constexpr int N = H * W;          // 114688
constexpr int P = B * N;          // 917504

constexpr int TS  = 16;           // output tile 16x16
constexpr int NT  = 256;          // one thread per output pixel
constexpr int RW  = 8;            // max source radius (covers |flow| <= 7)
constexpr int WIN = 32;           // TS + 2*RW
constexpr int NW  = WIN * WIN;    // 1024 window positions
constexpr int K   = 19;          // list capacity; P(cnt>19)~1e-8/px (exact fallback kept)
constexpr int CHB = 8;            // channels per staged chunk (4 fp16x2 planes)
constexpr int NCHUNK = C / CHB;   // 8
constexpr float FMAX = 7.0f;
constexpr int TX = W / TS, TY = H / TS;   // 28, 16
constexpr int TILES = B * TX * TY;        // 3584
constexpr int NXCD = 8;

// Phase-1 layout (words): fxy interleaved stride-33 rows [2112] | em [1024] | pk [19*256=4864] = 8000
// Phase-2 layout: two buffers x 1024 pos x 4 packed words = 8192 words.
// Total 8192 words = 32,768 B -> exactly 5 blocks/CU.
constexpr int L_FXY = 0, L_EM = 2112, L_PK = 3136;
constexpr int LDS_WORDS = 8192;

typedef __fp16 h2_t __attribute__((ext_vector_type(2)));
static __device__ __forceinline__ unsigned pk2(float a, float b) {
    h2_t h = __builtin_amdgcn_cvt_pkrtz(a, b);
    return __builtin_bit_cast(unsigned, h);
}
static __device__ __forceinline__ float2 up2(unsigned u) {
    h2_t h = __builtin_bit_cast(h2_t, u);
    return make_float2((float)h.x, (float)h.y);
}

__device__ int g_flag;            // #sources with |flow|>FMAX (deterministic per input)

__global__ void zero_flag_k() { g_flag = 0; }

__global__ __launch_bounds__(256) void flag_scan(const float* __restrict__ flow)
{
    int t = blockIdx.x * blockDim.x + threadIdx.x;
    if (t >= P) return;
    int b = t / N, p = t - b * N;
    float fdx = flow[(size_t)(b * 2 + 0) * N + p];
    float fdy = flow[(size_t)(b * 2 + 1) * N + p];
    if (fabsf(fdx) > FMAX || fabsf(fdy) > FMAX) atomicAdd(&g_flag, 1);
}

// Stage 8 channels of the 32x32 window: thread t owns positions 4t..4t+3
// (row = t>>3, col = 4*(t&7)): coalesced float4 loads, all 16B-aligned.
#define STAGE_LOAD(gg)                                                        \
    {                                                                         \
        const int cbase = (gg) * CHB;                                         \
        const int row = tid >> 3;                                             \
        const int sc0 = (tid & 7) * 4;                                        \
        const int sh = ty0 - RW + row;                                        \
        const int sc = tx0 - RW + sc0;                                        \
        const bool v = (sh >= 0) & (sh < H) & (sc >= 0) & (sc < W);           \
        const float* bp = xb + (sh * W + sc);                                 \
        _Pragma("unroll")                                                     \
        for (int ch = 0; ch < CHB; ++ch)                                      \
            fr[ch] = v ? *(const float4*)(bp + (size_t)(cbase + ch) * N)      \
                       : make_float4(0.f, 0.f, 0.f, 0.f);                     \
    }

// Pack to fp16 pairs, position-major [pos][plane0..3], XOR-block-swizzled.
#define STAGE_WRITE(bufsel)                                                   \
    {                                                                         \
        char* base = (char*)lds + (bufsel) * 16384;                           \
        _Pragma("unroll")                                                     \
        for (int k = 0; k < 4; ++k) {                                         \
            const unsigned pos = 4u * (unsigned)tid + (unsigned)k;            \
            const unsigned blk = pos ^ ((pos >> 3) & 7u);                     \
            uint4 wv;                                                         \
            wv.x = pk2(((const float*)&fr[0])[k], ((const float*)&fr[1])[k]); \
            wv.y = pk2(((const float*)&fr[2])[k], ((const float*)&fr[3])[k]); \
            wv.z = pk2(((const float*)&fr[4])[k], ((const float*)&fr[5])[k]); \
            wv.w = pk2(((const float*)&fr[6])[k], ((const float*)&fr[7])[k]); \
            *(uint4*)(base + blk * 16) = wv;                                  \
        }                                                                     \
    }

__global__ __launch_bounds__(NT) void softsplat_fused(
    const float* __restrict__ x,
    const float* __restrict__ flow,
    const float* __restrict__ metric,
    float* __restrict__ out,      // [B, C, N]
    float* __restrict__ den)      // [B, N]
{
    __shared__ float lds[LDS_WORDS];
    float*    s_fxy = lds + L_FXY;     // [row*33+col]*2 interleaved (fx,fy)
    float*    s_em  = lds + L_EM;      // [row*32+col]
    unsigned* s_pk  = (unsigned*)(lds + L_PK);   // packed (w_hi22 | pos10)

    // XCD-aware bijective swizzle (TILES % 8 == 0)
    int bid = blockIdx.x;
    bid = (bid % NXCD) * (TILES / NXCD) + bid / NXCD;

    const int b   = bid / (TX * TY);
    const int tp  = bid % (TX * TY);
    const int ty0 = (tp / TX) * TS;
    const int tx0 = (tp % TX) * TS;
    const int tid = threadIdx.x;

    const float* fxg = flow + (size_t)(b * 2 + 0) * N;
    const float* fyg = flow + (size_t)(b * 2 + 1) * N;
    const float* mg  = metric + (size_t)b * N;

    // ---- phase 1a: stage flow/metric window; track valid |flow| max ----
    float mymax = 0.f;
    for (int i = tid; i < NW; i += NT) {
        const int wy = i >> 5, wx = i & 31;
        const int sh = ty0 - RW + wy, sw = tx0 - RW + wx;
        float fdx = 1.0e9f, fdy = 0.f, em = 0.f;
        if (sh >= 0 && sh < H && sw >= 0 && sw < W) {
            const int sp = sh * W + sw;
            const float a = fxg[sp], bb = fyg[sp];
            if (fabsf(a) <= FMAX && fabsf(bb) <= FMAX) {
                fdx = a; fdy = bb; em = __expf(mg[sp]);
                mymax = fmaxf(mymax, fmaxf(fabsf(a), fabsf(bb)));
            }
        }
        const int fi = wy * 33 + wx;
        s_fxy[2 * fi] = fdx; s_fxy[2 * fi + 1] = fdy; s_em[i] = em;
    }
    // block |flow| max via wave reduce + list-area scratch (overwritten later)
    #pragma unroll
    for (int m = 1; m < 64; m <<= 1) mymax = fmaxf(mymax, __shfl_xor(mymax, m));
    if ((tid & 63) == 0) lds[L_PK + (tid >> 6)] = mymax;
    __syncthreads();
    const float M = fmaxf(fmaxf(lds[L_PK + 0], lds[L_PK + 1]),
                          fmaxf(lds[L_PK + 2], lds[L_PK + 3]));
    const int Rdyn = min(RW, (int)M + 1);   // source at offset d needs |flow| >= d-1
    __syncthreads();                        // scratch reads done before pk writes

    const int qxl = tid & (TS - 1), qyl = tid >> 4;
    const int qx = tx0 + qxl, qy = ty0 + qyl;
    const int q  = qy * W + qx;

    // ---- phase 1b: scan [-Rdyn,Rdyn]^2 -> packed per-thread list ----
    int cnt = 0;
    float dacc = 0.f;
    for (int dy = -Rdyn; dy <= Rdyn; ++dy) {
        const int lrow = qyl + RW + dy;
        for (int dx = -Rdyn; dx <= Rdyn; ++dx) {
            const int lcol = qxl + RW + dx;
            const int fi = lrow * 33 + lcol;
            const float fdx = s_fxy[2 * fi];
            const float tx = (float)(qx + dx) + fdx;
            const float x0f = floorf(tx);
            const int ddx = qx - (int)x0f;
            if ((unsigned)ddx > 1u) continue;
            const float fdy = s_fxy[2 * fi + 1];
            const float tyy = (float)(qy + dy) + fdy;
            const float y0f = floorf(tyy);
            const int ddy = qy - (int)y0f;
            if ((unsigned)ddy > 1u) continue;
            const float fxf = tx - x0f, fyf = tyy - y0f;
            const float wxf = ddx ? fxf : 1.f - fxf;
            const float wyf = ddy ? fyf : 1.f - fyf;
            const float w = wxf * wyf * s_em[lrow * WIN + lcol];
            if (cnt < K) {
                const unsigned pos = (unsigned)(lrow * WIN + lcol);   // 10 bits
                s_pk[cnt * NT + tid] = (__float_as_uint(w) & 0xFFFFFC00u) | pos;
            }
            cnt++;
            dacc += w;   // full-precision denominator
        }
    }
    for (int j = cnt; j < K; ++j)
        s_pk[j * NT + tid] = (unsigned)((qyl + RW) * WIN + (qxl + RW));  // w=0 pad

    // wave-uniform loop bound
    int km = cnt;
    #pragma unroll
    for (int m = 1; m < 64; m <<= 1) km = max(km, __shfl_xor(km, m));
    const int kwave = min(K, __builtin_amdgcn_readfirstlane(km));

    const int flag = g_flag;
    const float rn = (flag == 0) ? 1.f / (dacc + EPS) : 1.f;

    const float* xb = x + (size_t)b * C * N;
    float* ob = out + (size_t)b * C * N + q;
    den[(size_t)b * N + q] = dacc;

    // list -> registers; gather index pre-swizzled to a byte offset (read side
    // of the involution matches STAGE_WRITE's blk swizzle)
    unsigned rsp[K]; float rw_[K];
    #pragma unroll
    for (int j = 0; j < K; ++j) {
        const unsigned pk = s_pk[j * NT + tid];
        const unsigned pos = pk & 0x3FFu;
        rsp[j] = (pos ^ ((pos >> 3) & 7u)) << 4;
        rw_[j] = __uint_as_float(pk & 0xFFFFFC00u);
    }

    // ---- phase 1c: exact overflow fallback (statistically never) ----
    const bool ovf = (cnt > K);
    if (ovf) {
        for (int c = 0; c < C; ++c) {
            const float* xp = xb + (size_t)c * N;
            float a = 0.f;
            for (int dy = -Rdyn; dy <= Rdyn; ++dy) {
                const int lrow = qyl + RW + dy;
                for (int dx = -Rdyn; dx <= Rdyn; ++dx) {
                    const int lcol = qxl + RW + dx;
                    const int fi = lrow * 33 + lcol;
                    const float fdx = s_fxy[2 * fi];
                    const float tx = (float)(qx + dx) + fdx;
                    const float x0f = floorf(tx);
                    const int ddx = qx - (int)x0f;
                    if ((unsigned)ddx > 1u) continue;
                    const float fdy = s_fxy[2 * fi + 1];
                    const float tyy = (float)(qy + dy) + fdy;
                    const float y0f = floorf(tyy);
                    const int ddy = qy - (int)y0f;
                    if ((unsigned)ddy > 1u) continue;
                    const float fxf = tx - x0f, fyf = tyy - y0f;
                    const float wxf = ddx ? fxf : 1.f - fxf;
                    const float wyf = ddy ? fyf : 1.f - fyf;
                    a = fmaf(wxf * wyf * s_em[lrow * WIN + lcol],
                             xp[(qy + dy) * W + (qx + dx)], a);
                }
            }
            ob[(size_t)c * N] = a * rn;
        }
    }
    __syncthreads();   // phase-1 LDS released; reuse as fp16 staging buffers

    // ---- phase 2: double-buffered fp16x2 staging; one ds_read_b128 per j per 8ch ----
    float4 fr[CHB];
    STAGE_LOAD(0)
    STAGE_WRITE(0)
    __syncthreads();
    for (int g = 0; g < NCHUNK; ++g) {
        const char* bc = (const char*)lds + (g & 1) * 16384;
        if (g + 1 < NCHUNK) STAGE_LOAD(g + 1)   // issue early: HBM latency under compute
        float a0 = 0.f, a1 = 0.f, a2 = 0.f, a3 = 0.f;
        float a4 = 0.f, a5 = 0.f, a6 = 0.f, a7 = 0.f;
        #pragma unroll
        for (int j = 0; j < K; ++j) {
            if (j >= kwave) break;              // wave-uniform scalar branch
            const uint4 v = *(const uint4*)(bc + rsp[j]);
            const float wj = rw_[j];
            float2 p;
            p = up2(v.x); a0 = fmaf(wj, p.x, a0); a1 = fmaf(wj, p.y, a1);
            p = up2(v.y); a2 = fmaf(wj, p.x, a2); a3 = fmaf(wj, p.y, a3);
            p = up2(v.z); a4 = fmaf(wj, p.x, a4); a5 = fmaf(wj, p.y, a5);
            p = up2(v.w); a6 = fmaf(wj, p.x, a6); a7 = fmaf(wj, p.y, a7);
        }
        if (!ovf) {
            ob[(size_t)(g * CHB + 0) * N] = a0 * rn;
            ob[(size_t)(g * CHB + 1) * N] = a1 * rn;
            ob[(size_t)(g * CHB + 2) * N] = a2 * rn;
            ob[(size_t)(g * CHB + 3) * N] = a3 * rn;
            ob[(size_t)(g * CHB + 4) * N] = a4 * rn;
            ob[(size_t)(g * CHB + 5) * N] = a5 * rn;
            ob[(size_t)(g * CHB + 6) * N] = a6 * rn;
            ob[(size_t)(g * CHB + 7) * N] = a7 * rn;
        }
        if (g + 1 < NCHUNK) STAGE_WRITE((g & 1) ^ 1)   // write late, after compute
        __syncthreads();
    }
}

// Sources with |flow|>FMAX (exist iff g_flag!=0): global atomics onto raw accumulators.
__global__ __launch_bounds__(256) void softsplat_outlier(
    const float* __restrict__ x,
    const float* __restrict__ flow,
    const float* __restrict__ metric,
    float* __restrict__ out,
    float* __restrict__ den)
{
    int t = blockIdx.x * blockDim.x + threadIdx.x;
    if (t >= P) return;
    int b = t / N;
    int p = t - b * N;
    float fdx = flow[(size_t)(b * 2 + 0) * N + p];
    float fdy = flow[(size_t)(b * 2 + 1) * N + p];
    if (fabsf(fdx) <= FMAX && fabsf(fdy) <= FMAX) return;

    int h = p / W, w = p - h * W;
    float m = __expf(metric[(size_t)b * N + p]);
    float tx = (float)w + fdx, ty = (float)h + fdy;
    float x0f = floorf(tx), y0f = floorf(ty);
    int x0 = (int)x0f, y0 = (int)y0f, x1 = x0 + 1, y1 = y0 + 1;
    float fx = tx - x0f, fy = ty - y0f;
    float w00 = (1.f - fx) * (1.f - fy), w10 = fx * (1.f - fy);
    float w01 = (1.f - fx) * fy,         w11 = fx * fy;
    bool vx0 = (x0 >= 0) && (x0 < W), vx1 = (x1 >= 0) && (x1 < W);
    bool vy0 = (y0 >= 0) && (y0 < H), vy1 = (y1 >= 0) && (y1 < H);
    int cx0 = min(max(x0, 0), W - 1), cx1 = min(max(x1, 0), W - 1);
    int cy0 = min(max(y0, 0), H - 1), cy1 = min(max(y1, 0), H - 1);
    int i00 = cy0 * W + cx0, i10 = cy0 * W + cx1;
    int i01 = cy1 * W + cx0, i11 = cy1 * W + cx1;
    w00 = (vx0 && vy0) ? w00 * m : 0.f;
    w10 = (vx1 && vy0) ? w10 * m : 0.f;
    w01 = (vx0 && vy1) ? w01 * m : 0.f;
    w11 = (vx1 && vy1) ? w11 * m : 0.f;

    float* denb = den + (size_t)b * N;
    if (w00 != 0.f) atomicAdd(denb + i00, w00);
    if (w10 != 0.f) atomicAdd(denb + i10, w10);
    if (w01 != 0.f) atomicAdd(denb + i01, w01);
    if (w11 != 0.f) atomicAdd(denb + i11, w11);

    const float* xb = x + (size_t)b * C * N + p;
    float* ob = out + (size_t)b * C * N;
    for (int c = 0; c < C; ++c) {
        float v = xb[(size_t)c * N];
        float* o = ob + (size_t)c * N;
        if (w00 != 0.f) atomicAdd(o + i00, v * w00);
        if (w10 != 0.f) atomicAdd(o + i10, v * w10);
        if (w01 != 0.f) atomicAdd(o + i01, v * w01);
        if (w11 != 0.f) atomicAdd(o + i11, v * w11);
    }
}

// Runs only when outliers exist (g_flag!=0); otherwise fused already normalized.
__global__ __launch_bounds__(256) void softsplat_norm(
    float* __restrict__ out, const float* __restrict__ den)
{
    if (g_flag == 0) return;
    size_t t = (size_t)blockIdx.x * blockDim.x + threadIdx.x;  // one float4
    size_t e = t * 4;
    if (e >= (size_t)B * C * N) return;
    size_t b = e / ((size_t)C * N);
    size_t p = (e - b * (size_t)C * N) % N;   // N % 4 == 0

    float4 o = *reinterpret_cast<float4*>(out + e);
    const float4 d = *reinterpret_cast<const float4*>(den + b * N + p);
    o.x = o.x / (d.x + EPS);
    o.y = o.y / (d.y + EPS);
    o.z = o.z / (d.z + EPS);
    o.w = o.w / (d.w + EPS);
    *reinterpret_cast<float4*>(out + e) = o;
}

extern "C" void kernel_launch(void* const* d_in, const int* in_sizes, int n_in,
                              void* d_out, int out_size, void* d_ws, size_t ws_size,
                              hipStream_t stream) {
    const float* x      = (const float*)d_in[0];
    const float* flow   = (const float*)d_in[1];
    const float* metric = (const float*)d_in[2];
    float* out = (float*)d_out;
    float* den = (float*)d_ws;

    zero_flag_k<<<1, 1, 0, stream>>>();
    flag_scan<<<(P + 255) / 256, 256, 0, stream>>>(flow);

    softsplat_fused<<<TILES, NT, 0, stream>>>(x, flow, metric, out, den);

    softsplat_outlier<<<(P + 255) / 256, 256, 0, stream>>>(x, flow, metric, out, den);

    size_t nvec4 = (size_t)B * C * N / 4;
    softsplat_norm<<<(int)((nvec4 + 255) / 256), 256, 0, stream>>>(out, den);
}

// Round 14
// 238.713 us; speedup vs baseline: 10.7713x; 1.0533x over previous
//
#include <hip/hip_runtime.h>

#define EPS 1e-7f

constexpr int B = 8, C = 64, H = 256, W = 448;
constexpr int N = H * W;          // 114688
constexpr int P = B * N;          // 917504

constexpr int TS  = 16;           // output tile 16x16
constexpr int NT  = 256;          // one thread per output pixel
constexpr int RW  = 8;            // max source radius (covers |flow| <= 7)
constexpr int WIN = 32;           // TS + 2*RW
constexpr int NW  = WIN * WIN;    // 1024 window positions
constexpr int TGS = 40;           // s_tgt row stride: 4x16 lane block -> all 32 banks 2x (free)
constexpr int K   = 15;           // list capacity; P(cnt>15)~3e-6/px (exact fallback kept)
constexpr int CHB = 8;            // channels per staged chunk (4 fp16x2 planes)
constexpr int NCHUNK = C / CHB;   // 8
constexpr float FMAX = 7.0f;
constexpr int TX = W / TS, TY = H / TS;   // 28, 16
constexpr int TILES = B * TX * TY;        // 3584
constexpr int NXCD = 8;

// Phase-1 layout (words): tgt[32*40=1280] fx[1024] fy[1024] em[1024] pk[15*256=3840] = 8192
// Phase-2 layout: two buffers x 1024 pos x 4 packed words = 8192 words.
// 8192 words = 32,768 B -> exactly 5 blocks/CU.
constexpr int L_TGT = 0, L_FX = 1280, L_FY = 2304, L_EM = 3328, L_PK = 4352;
constexpr int LDS_WORDS = 8192;

typedef __fp16 h2_t __attribute__((ext_vector_type(2)));
static __device__ __forceinline__ unsigned pk2(float a, float b) {
    h2_t h = __builtin_amdgcn_cvt_pkrtz(a, b);
    return __builtin_bit_cast(unsigned, h);
}
static __device__ __forceinline__ float2 up2(unsigned u) {
    h2_t h = __builtin_bit_cast(h2_t, u);
    return make_float2((float)h.x, (float)h.y);
}

__device__ int g_flag;            // #sources with |flow|>FMAX (deterministic per input)

__global__ void zero_flag_k() { g_flag = 0; }

__global__ __launch_bounds__(256) void flag_scan(const float* __restrict__ flow)
{
    int t = blockIdx.x * blockDim.x + threadIdx.x;
    if (t >= P) return;
    int b = t / N, p = t - b * N;
    float fdx = flow[(size_t)(b * 2 + 0) * N + p];
    float fdy = flow[(size_t)(b * 2 + 1) * N + p];
    if (fabsf(fdx) > FMAX || fabsf(fdy) > FMAX) atomicAdd(&g_flag, 1);
}

// Stage 8 channels of the 32x32 window: thread t owns positions 4t..4t+3
// (row = t>>3, col = 4*(t&7)): coalesced float4 loads, all 16B-aligned.
#define STAGE_LOAD(gg)                                                        \
    {                                                                         \
        const int cbase = (gg) * CHB;                                         \
        const int row = tid >> 3;                                             \
        const int sc0 = (tid & 7) * 4;                                        \
        const int sh = ty0 - RW + row;                                        \
        const int sc = tx0 - RW + sc0;                                        \
        const bool v = (sh >= 0) & (sh < H) & (sc >= 0) & (sc < W);           \
        const float* bp = xb + (sh * W + sc);                                 \
        _Pragma("unroll")                                                     \
        for (int ch = 0; ch < CHB; ++ch)                                      \
            fr[ch] = v ? *(const float4*)(bp + (size_t)(cbase + ch) * N)      \
                       : make_float4(0.f, 0.f, 0.f, 0.f);                     \
    }

// Pack to fp16 pairs, position-major [pos][plane0..3], XOR-block-swizzled.
#define STAGE_WRITE(bufsel)                                                   \
    {                                                                         \
        char* base = (char*)lds + (bufsel) * 16384;                           \
        _Pragma("unroll")                                                     \
        for (int k = 0; k < 4; ++k) {                                         \
            const unsigned pos = 4u * (unsigned)tid + (unsigned)k;            \
            const unsigned blk = pos ^ ((pos >> 3) & 7u);                     \
            uint4 wv;                                                         \
            wv.x = pk2(((const float*)&fr[0])[k], ((const float*)&fr[1])[k]); \
            wv.y = pk2(((const float*)&fr[2])[k], ((const float*)&fr[3])[k]); \
            wv.z = pk2(((const float*)&fr[4])[k], ((const float*)&fr[5])[k]); \
            wv.w = pk2(((const float*)&fr[6])[k], ((const float*)&fr[7])[k]); \
            *(uint4*)(base + blk * 16) = wv;                                  \
        }                                                                     \
    }

__global__ __launch_bounds__(NT) void softsplat_fused(
    const float* __restrict__ x,
    const float* __restrict__ flow,
    const float* __restrict__ metric,
    float* __restrict__ out,      // [B, C, N]
    float* __restrict__ den)      // [B, N]
{
    __shared__ float lds[LDS_WORDS];
    unsigned* s_tgt = (unsigned*)(lds + L_TGT);  // [row*40+col]: (ty0+16)<<16 | (tx0+16)
    float*    s_fx  = lds + L_FX;                // frac x  [row*32+col]
    float*    s_fy  = lds + L_FY;                // frac y
    float*    s_em  = lds + L_EM;                // exp(metric)
    unsigned* s_pk  = (unsigned*)(lds + L_PK);   // packed (w_hi22 | pos10)

    // XCD-aware bijective swizzle (TILES % 8 == 0)
    int bid = blockIdx.x;
    bid = (bid % NXCD) * (TILES / NXCD) + bid / NXCD;

    const int b   = bid / (TX * TY);
    const int tp  = bid % (TX * TY);
    const int ty0 = (tp / TX) * TS;
    const int tx0 = (tp % TX) * TS;
    const int tid = threadIdx.x;

    const float* fxg = flow + (size_t)(b * 2 + 0) * N;
    const float* fyg = flow + (size_t)(b * 2 + 1) * N;
    const float* mg  = metric + (size_t)b * N;

    // ---- phase 1a: stage window; precompute target corner + fracs per source ----
    // floor(q+dx+f) == q+dx+floor(f) (bilinear weight continuous in frac, so the
    // reference's float-sum rounding differs by <=2e-5 in weight - negligible).
    float mymax = 0.f;
    for (int i = tid; i < NW; i += NT) {
        const int wy = i >> 5, wx = i & 31;
        const int sh = ty0 - RW + wy, sw = tx0 - RW + wx;
        unsigned t = 0xFFFFFFFFu;                // sentinel: never hits
        if (sh >= 0 && sh < H && sw >= 0 && sw < W) {
            const int sp = sh * W + sw;
            const float a = fxg[sp], bb = fyg[sp];
            if (fabsf(a) <= FMAX && fabsf(bb) <= FMAX) {
                const float xf = floorf(a), yf = floorf(bb);
                const int tx0g = sw + (int)xf + 16;   // [1,470] -> 16 bits
                const int ty0g = sh + (int)yf + 16;
                t = ((unsigned)ty0g << 16) | (unsigned)tx0g;
                s_fx[i] = a - xf;
                s_fy[i] = bb - yf;
                s_em[i] = __expf(mg[sp]);
                mymax = fmaxf(mymax, fmaxf(fabsf(a), fabsf(bb)));
            }
        }
        s_tgt[wy * TGS + wx] = t;
    }
    // block |flow| max via wave reduce + list-area scratch (overwritten later)
    #pragma unroll
    for (int m = 1; m < 64; m <<= 1) mymax = fmaxf(mymax, __shfl_xor(mymax, m));
    if ((tid & 63) == 0) lds[L_PK + (tid >> 6)] = mymax;
    __syncthreads();
    const float M = fmaxf(fmaxf(lds[L_PK + 0], lds[L_PK + 1]),
                          fmaxf(lds[L_PK + 2], lds[L_PK + 3]));
    const int Rdyn = min(RW, (int)M + 1);   // source at offset d needs |flow| >= d-1
    __syncthreads();                        // scratch reads done before pk writes

    const int qxl = tid & (TS - 1), qyl = tid >> 4;
    const int qx = tx0 + qxl, qy = ty0 + qyl;
    const int q  = qy * W + qx;
    const unsigned qx16 = (unsigned)(qx + 16), qy16 = (unsigned)(qy + 16);

    // ---- phase 1b: scan [-Rdyn,Rdyn]^2; 7-op reject, full math only on hits ----
    int cnt = 0;
    float dacc = 0.f;
    for (int dy = -Rdyn; dy <= Rdyn; ++dy) {
        const int lrow = qyl + RW + dy;
        const int trow = lrow * TGS + (qxl + RW);
        for (int dx = -Rdyn; dx <= Rdyn; ++dx) {
            const unsigned t = s_tgt[trow + dx];
            const unsigned du = qx16 - (t & 0xFFFFu);
            const unsigned dv = qy16 - (t >> 16);
            if (max(du, dv) > 1u) continue;
            const int fi = lrow * WIN + (qxl + RW + dx);
            const float fxf = s_fx[fi], fyf = s_fy[fi];
            const float wxf = du ? fxf : 1.f - fxf;
            const float wyf = dv ? fyf : 1.f - fyf;
            const float w = wxf * wyf * s_em[fi];
            if (cnt < K)
                s_pk[cnt * NT + tid] = (__float_as_uint(w) & 0xFFFFFC00u) | (unsigned)fi;
            cnt++;
            dacc += w;   // full-precision denominator
        }
    }
    for (int j = cnt; j < K; ++j)
        s_pk[j * NT + tid] = (unsigned)((qyl + RW) * WIN + (qxl + RW));  // w=0 pad

    // wave-uniform loop bound
    int km = cnt;
    #pragma unroll
    for (int m = 1; m < 64; m <<= 1) km = max(km, __shfl_xor(km, m));
    const int kwave = min(K, __builtin_amdgcn_readfirstlane(km));

    const int flag = g_flag;
    const float rn = (flag == 0) ? 1.f / (dacc + EPS) : 1.f;

    const float* xb = x + (size_t)b * C * N;
    float* ob = out + (size_t)b * C * N + q;
    den[(size_t)b * N + q] = dacc;

    // list -> registers; gather index pre-swizzled; weight pre-scaled by rn
    unsigned rsp[K]; float rw_[K];
    #pragma unroll
    for (int j = 0; j < K; ++j) {
        const unsigned pk = s_pk[j * NT + tid];
        const unsigned pos = pk & 0x3FFu;
        rsp[j] = (pos ^ ((pos >> 3) & 7u)) << 4;
        rw_[j] = __uint_as_float(pk & 0xFFFFFC00u) * rn;
    }

    // ---- phase 1c: exact overflow fallback (statistically never) ----
    const bool ovf = (cnt > K);
    if (ovf) {
        for (int c = 0; c < C; ++c) {
            const float* xp = xb + (size_t)c * N;
            float a = 0.f;
            for (int dy = -Rdyn; dy <= Rdyn; ++dy) {
                const int lrow = qyl + RW + dy;
                const int trow = lrow * TGS + (qxl + RW);
                for (int dx = -Rdyn; dx <= Rdyn; ++dx) {
                    const unsigned t = s_tgt[trow + dx];
                    const unsigned du = qx16 - (t & 0xFFFFu);
                    const unsigned dv = qy16 - (t >> 16);
                    if (max(du, dv) > 1u) continue;
                    const int fi = lrow * WIN + (qxl + RW + dx);
                    const float fxf = s_fx[fi], fyf = s_fy[fi];
                    const float wxf = du ? fxf : 1.f - fxf;
                    const float wyf = dv ? fyf : 1.f - fyf;
                    a = fmaf(wxf * wyf * s_em[fi], xp[(qy + dy) * W + (qx + dx)], a);
                }
            }
            ob[(size_t)c * N] = a * rn;
        }
    }
    __syncthreads();   // phase-1 LDS released; reuse as fp16 staging buffers

    // ---- phase 2: double-buffered fp16x2 staging; one ds_read_b128 per j per 8ch ----
    float4 fr[CHB];
    STAGE_LOAD(0)
    STAGE_WRITE(0)
    __syncthreads();
    for (int g = 0; g < NCHUNK; ++g) {
        const char* bc = (const char*)lds + (g & 1) * 16384;
        if (g + 1 < NCHUNK) STAGE_LOAD(g + 1)   // issue early: HBM latency under compute
        float a0 = 0.f, a1 = 0.f, a2 = 0.f, a3 = 0.f;
        float a4 = 0.f, a5 = 0.f, a6 = 0.f, a7 = 0.f;
        #pragma unroll
        for (int j = 0; j < K; ++j) {
            if (j >= kwave) break;              // wave-uniform scalar branch
            const uint4 v = *(const uint4*)(bc + rsp[j]);
            const float wj = rw_[j];
            float2 p;
            p = up2(v.x); a0 = fmaf(wj, p.x, a0); a1 = fmaf(wj, p.y, a1);
            p = up2(v.y); a2 = fmaf(wj, p.x, a2); a3 = fmaf(wj, p.y, a3);
            p = up2(v.z); a4 = fmaf(wj, p.x, a4); a5 = fmaf(wj, p.y, a5);
            p = up2(v.w); a6 = fmaf(wj, p.x, a6); a7 = fmaf(wj, p.y, a7);
        }
        if (!ovf) {
            ob[(size_t)(g * CHB + 0) * N] = a0;
            ob[(size_t)(g * CHB + 1) * N] = a1;
            ob[(size_t)(g * CHB + 2) * N] = a2;
            ob[(size_t)(g * CHB + 3) * N] = a3;
            ob[(size_t)(g * CHB + 4) * N] = a4;
            ob[(size_t)(g * CHB + 5) * N] = a5;
            ob[(size_t)(g * CHB + 6) * N] = a6;
            ob[(size_t)(g * CHB + 7) * N] = a7;
        }
        if (g + 1 < NCHUNK) STAGE_WRITE((g & 1) ^ 1)   // write late, after compute
        __syncthreads();
    }
}

// Sources with |flow|>FMAX (exist iff g_flag!=0): global atomics onto raw accumulators.
__global__ __launch_bounds__(256) void softsplat_outlier(
    const float* __restrict__ x,
    const float* __restrict__ flow,
    const float* __restrict__ metric,
    float* __restrict__ out,
    float* __restrict__ den)
{
    int t = blockIdx.x * blockDim.x + threadIdx.x;
    if (t >= P) return;
    int b = t / N;
    int p = t - b * N;
    float fdx = flow[(size_t)(b * 2 + 0) * N + p];
    float fdy = flow[(size_t)(b * 2 + 1) * N + p];
    if (fabsf(fdx) <= FMAX && fabsf(fdy) <= FMAX) return;

    int h = p / W, w = p - h * W;
    float m = __expf(metric[(size_t)b * N + p]);
    float tx = (float)w + fdx, ty = (float)h + fdy;
    float x0f = floorf(tx), y0f = floorf(ty);
    int x0 = (int)x0f, y0 = (int)y0f, x1 = x0 + 1, y1 = y0 + 1;
    float fx = tx - x0f, fy = ty - y0f;
    float w00 = (1.f - fx) * (1.f - fy), w10 = fx * (1.f - fy);
    float w01 = (1.f - fx) * fy,         w11 = fx * fy;
    bool vx0 = (x0 >= 0) && (x0 < W), vx1 = (x1 >= 0) && (x1 < W);
    bool vy0 = (y0 >= 0) && (y0 < H), vy1 = (y1 >= 0) && (y1 < H);
    int cx0 = min(max(x0, 0), W - 1), cx1 = min(max(x1, 0), W - 1);
    int cy0 = min(max(y0, 0), H - 1), cy1 = min(max(y1, 0), H - 1);
    int i00 = cy0 * W + cx0, i10 = cy0 * W + cx1;
    int i01 = cy1 * W + cx0, i11 = cy1 * W + cx1;
    w00 = (vx0 && vy0) ? w00 * m : 0.f;
    w10 = (vx1 && vy0) ? w10 * m : 0.f;
    w01 = (vx0 && vy1) ? w01 * m : 0.f;
    w11 = (vx1 && vy1) ? w11 * m : 0.f;

    float* denb = den + (size_t)b * N;
    if (w00 != 0.f) atomicAdd(denb + i00, w00);
    if (w10 != 0.f) atomicAdd(denb + i10, w10);
    if (w01 != 0.f) atomicAdd(denb + i01, w01);
    if (w11 != 0.f) atomicAdd(denb + i11, w11);

    const float* xb = x + (size_t)b * C * N + p;
    float* ob = out + (size_t)b * C * N;
    for (int c = 0; c < C; ++c) {
        float v = xb[(size_t)c * N];
        float* o = ob + (size_t)c * N;
        if (w00 != 0.f) atomicAdd(o + i00, v * w00);
        if (w10 != 0.f) atomicAdd(o + i10, v * w10);
        if (w01 != 0.f) atomicAdd(o + i01, v * w01);
        if (w11 != 0.f) atomicAdd(o + i11, v * w11);
    }
}

// Runs only when outliers exist (g_flag!=0); otherwise fused already normalized.
__global__ __launch_bounds__(256) void softsplat_norm(
    float* __restrict__ out, const float* __restrict__ den)
{
    if (g_flag == 0) return;
    size_t t = (size_t)blockIdx.x * blockDim.x + threadIdx.x;  // one float4
    size_t e = t * 4;
    if (e >= (size_t)B * C * N) return;
    size_t b = e / ((size_t)C * N);
    size_t p = (e - b * (size_t)C * N) % N;   // N % 4 == 0

    float4 o = *reinterpret_cast<float4*>(out + e);
    const float4 d = *reinterpret_cast<const float4*>(den + b * N + p);
    o.x = o.x / (d.x + EPS);
    o.y = o.y / (d.y + EPS);
    o.z = o.z / (d.z + EPS);
    o.w = o.w / (d.w + EPS);
    *reinterpret_cast<float4*>(out + e) = o;
}

extern "C" void kernel_launch(void* const* d_in, const int* in_sizes, int n_in,
                              void* d_out, int out_size, void* d_ws, size_t ws_size,
                              hipStream_t stream) {
    const float* x      = (const float*)d_in[0];
    const float* flow   = (const float*)d_in[1];
    const float* metric = (const float*)d_in[2];
    float* out = (float*)d_out;
    float* den = (float*)d_ws;

    zero_flag_k<<<1, 1, 0, stream>>>();
    flag_scan<<<(P + 255) / 256, 256, 0, stream>>>(flow);

    softsplat_fused<<<TILES, NT, 0, stream>>>(x, flow, metric, out, den);

    softsplat_outlier<<<(P + 255) / 256, 256, 0, stream>>>(x, flow, metric, out, den);

    size_t nvec4 = (size_t)B * C * N / 4;
    softsplat_norm<<<(int)((nvec4 + 255) / 256), 256, 0, stream>>>(out, den);
}